// Round 4
// baseline (700.060 us; speedup 1.0000x reference)
//
#include <hip/hip_runtime.h>
#include <hip/hip_bf16.h>
#include <stdint.h>

typedef __hip_bfloat16 bf16;

// ---------------- threefry2x32 (exact JAX semantics) ----------------
struct TF2 { unsigned a, b; };
__host__ __device__ constexpr unsigned rotl32(unsigned v, int r) {
  return (v << r) | (v >> (32 - r));
}
__host__ __device__ constexpr TF2 tf2x32(unsigned k0, unsigned k1, unsigned x0, unsigned x1) {
  unsigned ks2 = k0 ^ k1 ^ 0x1BD11BDAu;
  x0 += k0; x1 += k1;
  const int ra[4] = {13, 15, 26, 6};
  const int rb[4] = {17, 29, 16, 24};
  for (int i = 0; i < 4; i++) { x0 += x1; x1 = rotl32(x1, ra[i]); x1 ^= x0; }
  x0 += k1; x1 += ks2 + 1u;
  for (int i = 0; i < 4; i++) { x0 += x1; x1 = rotl32(x1, rb[i]); x1 ^= x0; }
  x0 += ks2; x1 += k0 + 2u;
  for (int i = 0; i < 4; i++) { x0 += x1; x1 = rotl32(x1, ra[i]); x1 ^= x0; }
  x0 += k0; x1 += k1 + 3u;
  for (int i = 0; i < 4; i++) { x0 += x1; x1 = rotl32(x1, rb[i]); x1 ^= x0; }
  x0 += k1; x1 += ks2 + 4u;
  for (int i = 0; i < 4; i++) { x0 += x1; x1 = rotl32(x1, ra[i]); x1 ^= x0; }
  x0 += ks2; x1 += k0 + 5u;
  return TF2{x0, x1};
}
// gkey = fold_in(key(0), 12345) = threefry2x32([0,0],[0,12345]) — config-independent
constexpr unsigned GK0 = tf2x32(0u, 0u, 0u, 12345u).a;
constexpr unsigned GK1 = tf2x32(0u, 0u, 0u, 12345u).b;

// JAX threefry_partitionable=True (default since 0.4.30) 32-bit random bits:
// element i uses counter (hi32(i), lo32(i)) and XOR-folds the two output words.
__device__ __forceinline__ float gumbel_at(unsigned j) {
  TF2 r = tf2x32(GK0, GK1, 0u, j);
  unsigned bits = r.a ^ r.b;
  float u = __uint_as_float((bits >> 9) | 0x3f800000u) - 1.0f;
  u = fmaxf(1.17549435e-38f, u + 1.17549435e-38f);   // minval = finfo(f32).tiny
  return -logf(-logf(u));
}

__device__ __forceinline__ float sigm(float x) { return 1.0f / (1.0f + expf(-x)); }

// ---------------- dtype-dispatch IO trait ----------------
template<int MODE> struct IO;
template<> struct IO<0> {   // float32 buffers
  static __device__ __forceinline__ float ld(const void* p, int i) {
    return ((const float*)p)[i];
  }
  static __device__ __forceinline__ void st(void* p, int i, float v) {
    ((float*)p)[i] = v;
  }
};
template<> struct IO<1> {   // bfloat16 buffers
  static __device__ __forceinline__ float ld(const void* p, int i) {
    return __bfloat162float(((const bf16*)p)[i]);
  }
  static __device__ __forceinline__ void st(void* p, int i, float v) {
    ((bf16*)p)[i] = __float2bfloat16(v);
  }
};

// ---------------- dtype probe: bf16-decode of f32 data explodes ----------------
__global__ void k_detect(const void* inp, int* flag) {
  __shared__ int bad;
  if (threadIdx.x == 0) bad = 0;
  __syncthreads();
  const unsigned short* u = (const unsigned short*)inp;
  for (int i = threadIdx.x; i < 1024; i += 256) {
    float v = __uint_as_float(((unsigned)u[i]) << 16);
    if (!(fabsf(v) < 64.f)) atomicOr(&bad, 1);   // NaN also lands here
  }
  __syncthreads();
  if (threadIdx.x == 0) *flag = bad ? 0 : 1;     // 0 = f32, 1 = bf16
}

// ============ Fully fused SCOFF cell: one block = 2 batches = 16 rows ============
template<int MODE>
__global__ __launch_bounds__(256, 2)
void k_scoff(const int* __restrict__ flag,
             const void* __restrict__ inp, const void* __restrict__ hx,
             const void* __restrict__ cx,
             const void* __restrict__ Wq_i, const void* __restrict__ Wk_i,
             const void* __restrict__ Wv_i,
             const void* __restrict__ Wq_c, const void* __restrict__ Wk_c,
             const void* __restrict__ Wv_c, const void* __restrict__ Wf_c,
             const void* __restrict__ bf_c, const void* __restrict__ Wg_c,
             const void* __restrict__ bg_c,
             const void* __restrict__ W_ih, const void* __restrict__ W_hh,
             const void* __restrict__ b_ih, const void* __restrict__ b_hh,
             const void* __restrict__ W_read, const void* __restrict__ W_write,
             void* __restrict__ out_hx, void* __restrict__ out_cx,
             void* __restrict__ out_mask, void* __restrict__ out_bm,
             void* __restrict__ out_ta)
{
  if (*flag != MODE) return;   // wrong-dtype instantiation: uniform exit, no barriers hit

  const int t  = threadIdx.x;
  const int n0 = blockIdx.x * 16;
  const int gbase = n0 * 128;

  __shared__ float inps_os[2048];
  __shared__ float As[4096];
  __shared__ float Bs[8320];
  __shared__ float attbuf[512];
  __shared__ float hrs[256];
  __shared__ float m8[16];
  __shared__ int   msh[16];

  float* const qs  = Bs;
  float* const ksl = Bs + 1024;
  float* const vs  = Bs + 2048;
  float* const hxs = Bs + 4096;

  // =================== P0: stage hx, inp ===================
  if constexpr (MODE == 1) {
    const unsigned* hx32 = (const unsigned*)((const bf16*)hx + gbase);
    const unsigned* in32 = (const unsigned*)((const bf16*)inp + gbase);
    for (int idx = t; idx < 1024; idx += 256) {
      unsigned wh = hx32[idx], wi = in32[idx];
      hxs[2 * idx]         = __uint_as_float(wh << 16);
      hxs[2 * idx + 1]     = __uint_as_float(wh & 0xffff0000u);
      inps_os[2 * idx]     = __uint_as_float(wi << 16);
      inps_os[2 * idx + 1] = __uint_as_float(wi & 0xffff0000u);
    }
  } else {
    const float* hxf = (const float*)hx + gbase;
    const float* inf_ = (const float*)inp + gbase;
    for (int idx = t; idx < 512; idx += 256) {
      *reinterpret_cast<float4*>(&hxs[idx * 4]) =
          *reinterpret_cast<const float4*>(hxf + idx * 4);
      *reinterpret_cast<float4*>(&inps_os[idx * 4]) =
          *reinterpret_cast<const float4*>(inf_ + idx * 4);
    }
  }
  __syncthreads();

  // =================== P1a: projections qs/ksl/vs, A(hx), h_read ===================
  for (int idx = t; idx < 1024; idx += 256) {
    int k16 = idx >> 6, d = idx & 63;
    float aq = 0.f, ak = 0.f;
#pragma unroll 8
    for (int i = 0; i < 128; i++) {
      aq += hxs[k16 * 128 + i]     * IO<MODE>::ld(Wq_i, i * 64 + d);
      ak += inps_os[k16 * 128 + i] * IO<MODE>::ld(Wk_i, i * 64 + d);
    }
    qs[idx] = aq; ksl[idx] = ak;
  }
  for (int idx = t; idx < 2048; idx += 256) {
    int n16 = idx >> 7, j = idx & 127;
    float a = 0.f;
#pragma unroll 8
    for (int i = 0; i < 128; i++) a += inps_os[n16 * 128 + i] * IO<MODE>::ld(Wv_i, i * 128 + j);
    vs[idx] = a;
  }
  for (int idx = t; idx < 2048; idx += 256) {
    int i = idx >> 4, r = idx & 15;
    As[(128 + i) * 16 + r] = hxs[r * 128 + i];
  }
  {
    int n16 = t >> 4, d = t & 15;
    float a = 0.f;
#pragma unroll 8
    for (int i = 0; i < 128; i++) a += hxs[n16 * 128 + i] * IO<MODE>::ld(W_read, i * 16 + d);
    hrs[t] = a;
  }
  __syncthreads();

  // =================== P1b: scores, softmax, top-k, inp_use -> A ===================
  if (t < 128) {
    int b2 = t >> 6, k = (t >> 3) & 7, n = t & 7;
    float sc = 0.f;
#pragma unroll
    for (int d = 0; d < 64; d++) sc += qs[(b2 * 8 + k) * 64 + d] * ksl[(b2 * 8 + n) * 64 + d];
    attbuf[b2 * 72 + k * 9 + n] = sc * 0.125f;
  } else if (t < 144) {
    int u = t - 128, b2 = u >> 3, k = u & 7;
    attbuf[b2 * 72 + k * 9 + 8] = 0.f;
  }
  __syncthreads();
  if (t < 16) {
    int b2 = t >> 3, k = t & 7;
    float* row = &attbuf[b2 * 72 + k * 9];
    float mx = row[0];
    for (int n = 1; n < 9; n++) mx = fmaxf(mx, row[n]);
    float e[9], ssum = 0.f;
    for (int n = 0; n < 9; n++) { e[n] = expf(row[n] - mx); ssum += e[n]; }
    for (int n = 0; n < 9; n++) row[n] = e[n] / ssum;
  }
  __syncthreads();
  if (t < 2) {
    bool taken[8] = {};
    for (int dd = 0; dd < 3; dd++) {
      int bi = 0; float bv = -1e30f;
      for (int k = 0; k < 8; k++) {
        float v = attbuf[t * 72 + k * 9 + 0];
        if (!taken[k] && v > bv) { bv = v; bi = k; }
      }
      taken[bi] = true;
    }
    for (int k = 0; k < 8; k++) m8[t * 8 + k] = taken[k] ? 0.f : 1.f;
  }
  __syncthreads();
  for (int idx = t; idx < 2048; idx += 256) {
    int n16 = idx >> 7, j = idx & 127, b2 = n16 >> 3, k = n16 & 7;
    float a = 0.f;
#pragma unroll
    for (int n = 0; n < 8; n++) a += attbuf[b2 * 72 + k * 9 + n] * vs[(b2 * 8 + n) * 128 + j];
    As[j * 16 + n16] = a;
    IO<MODE>::st(out_mask, gbase + idx, m8[n16]);
  }
  if (t < 16) IO<MODE>::st(out_bm, n0 + t, m8[t]);
  __syncthreads();

  // =================== P2: gates GEMM (f32) + LSTM pointwise ===================
  const int s = t & 127, rg = t >> 7;
  float cvals[8];
#pragma unroll
  for (int j = 0; j < 8; j++) cvals[j] = IO<MODE>::ld(cx, (n0 + rg * 8 + j) * 128 + s);

  float ht[8][4], ct[8][4];
  const int sq = t >> 1, hf = t & 1;

#pragma unroll
  for (int m = 0; m < 4; m++) {
    float acc[8][4];
#pragma unroll
    for (int j = 0; j < 8; j++)
#pragma unroll
      for (int q = 0; q < 4; q++) acc[j][q] = 0.f;

    for (int kc = 0; kc < 256; kc += 16) {
      __syncthreads();
      {  // stage B chunk: Bs[kk][s*4+q] = W[m, q*128+s, kc'+kk], kk = hf*8+c
        const int kb = (kc & 127) + hf * 8;
        float e[4][8];
        if constexpr (MODE == 1) {
          const bf16* Wsrc = (const bf16*)((kc < 128) ? W_ih : W_hh);
          uint4 wq[4];
#pragma unroll
          for (int q = 0; q < 4; q++)
            wq[q] = *reinterpret_cast<const uint4*>(Wsrc + ((m * 512 + q * 128 + sq) << 7) + kb);
#pragma unroll
          for (int q = 0; q < 4; q++) {
            unsigned w0 = wq[q].x, w1 = wq[q].y, w2 = wq[q].z, w3 = wq[q].w;
            e[q][0] = __uint_as_float(w0 << 16); e[q][1] = __uint_as_float(w0 & 0xffff0000u);
            e[q][2] = __uint_as_float(w1 << 16); e[q][3] = __uint_as_float(w1 & 0xffff0000u);
            e[q][4] = __uint_as_float(w2 << 16); e[q][5] = __uint_as_float(w2 & 0xffff0000u);
            e[q][6] = __uint_as_float(w3 << 16); e[q][7] = __uint_as_float(w3 & 0xffff0000u);
          }
        } else {
          const float* Wsrc = (const float*)((kc < 128) ? W_ih : W_hh);
#pragma unroll
          for (int q = 0; q < 4; q++) {
            const float* rowp = Wsrc + ((m * 512 + q * 128 + sq) << 7) + kb;
            float4 lo = *reinterpret_cast<const float4*>(rowp);
            float4 hi = *reinterpret_cast<const float4*>(rowp + 4);
            e[q][0] = lo.x; e[q][1] = lo.y; e[q][2] = lo.z; e[q][3] = lo.w;
            e[q][4] = hi.x; e[q][5] = hi.y; e[q][6] = hi.z; e[q][7] = hi.w;
          }
        }
#pragma unroll
        for (int c = 0; c < 8; c++) {
          float4 v; v.x = e[0][c]; v.y = e[1][c]; v.z = e[2][c]; v.w = e[3][c];
          *reinterpret_cast<float4*>(&Bs[(hf * 8 + c) * 520 + sq * 4]) = v;
        }
      }
      __syncthreads();
#pragma unroll
      for (int kk = 0; kk < 16; kk++) {
        const float4* ap = reinterpret_cast<const float4*>(&As[(kc + kk) * 16 + rg * 8]);
        float4 a0 = ap[0], a1 = ap[1];
        float4 bb = *reinterpret_cast<const float4*>(&Bs[kk * 520 + s * 4]);
        float av[8] = {a0.x, a0.y, a0.z, a0.w, a1.x, a1.y, a1.z, a1.w};
#pragma unroll
        for (int j = 0; j < 8; j++) {
          acc[j][0] += av[j] * bb.x;
          acc[j][1] += av[j] * bb.y;
          acc[j][2] += av[j] * bb.z;
          acc[j][3] += av[j] * bb.w;
        }
      }
    }
    float badd[4];
#pragma unroll
    for (int q = 0; q < 4; q++)
      badd[q] = IO<MODE>::ld(b_ih, m * 512 + q * 128 + s) +
                IO<MODE>::ld(b_hh, m * 512 + q * 128 + s);
#pragma unroll
    for (int j = 0; j < 8; j++) {
      float ig = acc[j][0] + badd[0];
      float fg = acc[j][1] + badd[1];
      float gg = acc[j][2] + badd[2];
      float og = acc[j][3] + badd[3];
      float c_t = sigm(fg) * cvals[j] + sigm(ig) * tanhf(gg);
      float h_t = sigm(og) * tanhf(c_t);
      ct[j][m] = c_t; ht[j][m] = h_t;
    }
  }

  // =================== P3: template selection + cx out ===================
  __syncthreads();
#pragma unroll
  for (int j = 0; j < 8; j++) {
    int r = rg * 8 + j;
#pragma unroll
    for (int m = 0; m < 4; m++) Bs[r * 520 + m * 128 + s] = ht[j][m];
  }
  __syncthreads();
  {
    const int row = t >> 4, d = t & 15;
    const float hr = hrs[t];
    float lg[4];
#pragma unroll
    for (int m = 0; m < 4; m++) {
      float wk = 0.f;
#pragma unroll 8
      for (int ss = 0; ss < 128; ss++)
        wk += Bs[row * 520 + m * 128 + ss] * IO<MODE>::ld(W_write, (m * 128 + ss) * 16 + d);
      float p = hr * wk;
      p += __shfl_xor(p, 1, 64);
      p += __shfl_xor(p, 2, 64);
      p += __shfl_xor(p, 4, 64);
      p += __shfl_xor(p, 8, 64);
      lg[m] = p;
    }
    if (d == 0) {
      const int n = n0 + row;
      float z[4];
#pragma unroll
      for (int m = 0; m < 4; m++) z[m] = lg[m] + gumbel_at((unsigned)(n * 4 + m));
      int ms = 0; float best = z[0];
#pragma unroll
      for (int m = 1; m < 4; m++) if (z[m] > best) { best = z[m]; ms = m; }
      msh[row] = ms;
#pragma unroll
      for (int m = 0; m < 4; m++)
        IO<MODE>::st(out_ta, n * 4 + m, (m == ms) ? 1.0f : 0.0f);
    }
  }
  __syncthreads();
#pragma unroll
  for (int j = 0; j < 8; j++) {
    int r = rg * 8 + j;
    int ms = msh[r];
    float cv = ct[j][0];
    if (ms == 1) cv = ct[j][1];
    else if (ms == 2) cv = ct[j][2];
    else if (ms == 3) cv = ct[j][3];
    float co = (m8[r] != 0.f) ? cv : cvals[j];
    IO<MODE>::st(out_cx, (n0 + r) * 128 + s, co);
  }

  // =================== P4: communication attention + hx out ===================
  __syncthreads();
  for (int idx = t; idx < 2048; idx += 256) {
    int r = idx >> 7, col = idx & 127;
    As[idx] = Bs[r * 520 + msh[r] * 128 + col];
  }
  __syncthreads();
  for (int idx = t; idx < 2048; idx += 256) {
    int r = idx >> 7, col = idx & 127;
    float aq = 0.f, ak = 0.f, av = 0.f;
#pragma unroll 8
    for (int i = 0; i < 128; i++) {
      float h = As[r * 128 + i];
      aq += h * IO<MODE>::ld(Wq_c, i * 128 + col);
      ak += h * IO<MODE>::ld(Wk_c, i * 128 + col);
      av += h * IO<MODE>::ld(Wv_c, i * 128 + col);
    }
    Bs[idx] = aq; Bs[2048 + idx] = ak; Bs[4096 + idx] = av;
  }
  __syncthreads();
  if (t < 64) {
    int b2 = t >> 5, h = (t >> 3) & 3, q = t & 7;
    float sc[8];
#pragma unroll
    for (int kq = 0; kq < 8; kq++) {
      float a = 0.f;
#pragma unroll
      for (int d = 0; d < 32; d++)
        a += Bs[(b2 * 8 + q) * 128 + h * 32 + d] * Bs[2048 + (b2 * 8 + kq) * 128 + h * 32 + d];
      sc[kq] = a * 0.17677669529663688110f;
    }
    float mx = sc[0];
#pragma unroll
    for (int kq = 1; kq < 8; kq++) mx = fmaxf(mx, sc[kq]);
    float e[8], ssum = 0.f;
#pragma unroll
    for (int kq = 0; kq < 8; kq++) { e[kq] = expf(sc[kq] - mx); ssum += e[kq]; }
#pragma unroll
    for (int kq = 0; kq < 8; kq++)
      attbuf[((b2 * 4 + h) * 8 + q) * 8 + kq] = e[kq] / ssum;
  }
  __syncthreads();
  for (int idx = t; idx < 2048; idx += 256) {
    int r = idx >> 7, col = idx & 127, b2 = r >> 3, q = r & 7, h = col >> 5;
    float a = 0.f;
#pragma unroll
    for (int kq = 0; kq < 8; kq++)
      a += attbuf[((b2 * 4 + h) * 8 + q) * 8 + kq] * Bs[4096 + (b2 * 8 + kq) * 128 + col];
    inps_os[idx] = a;
  }
  __syncthreads();
  for (int idx = t; idx < 2048; idx += 256) {
    int r = idx >> 7, col = idx & 127;
    float af = IO<MODE>::ld(bf_c, col);
    float ag = IO<MODE>::ld(bg_c, col);
#pragma unroll 8
    for (int d = 0; d < 128; d++) {
      float o = inps_os[r * 128 + d];
      af += o * IO<MODE>::ld(Wf_c, d * 128 + col);
      ag += o * IO<MODE>::ld(Wg_c, d * 128 + col);
    }
    float comm = sigm(ag) * tanhf(af);
    float hv = (m8[r] != 0.f) ? (As[r * 128 + col] + comm)
                              : IO<MODE>::ld(hx, gbase + idx);
    IO<MODE>::st(out_hx, gbase + idx, hv);
  }
}

// ============================ launch ============================
extern "C" void kernel_launch(void* const* d_in, const int* in_sizes, int n_in,
                              void* d_out, int out_size, void* d_ws, size_t ws_size,
                              hipStream_t stream) {
  const void* inp     = d_in[0];
  const void* hx      = d_in[1];
  const void* cx      = d_in[2];
  const void* Wq_i    = d_in[3];
  const void* Wk_i    = d_in[4];
  const void* Wv_i    = d_in[5];
  const void* Wq_c    = d_in[6];
  const void* Wk_c    = d_in[7];
  const void* Wv_c    = d_in[8];
  const void* Wf_c    = d_in[9];
  const void* bf_c    = d_in[10];
  const void* Wg_c    = d_in[11];
  const void* bg_c    = d_in[12];
  const void* W_ih    = d_in[13];
  const void* W_hh    = d_in[14];
  const void* b_ih    = d_in[15];
  const void* b_hh    = d_in[16];
  const void* W_read  = d_in[17];
  const void* W_write = d_in[18];

  int* flag = (int*)d_ws;

  k_detect<<<1, 256, 0, stream>>>(inp, flag);

  auto off_f32 = [&](int e) -> void* { return (void*)((float*)d_out + e); };
  auto off_b16 = [&](int e) -> void* { return (void*)((bf16*)d_out + e); };

  k_scoff<0><<<1024, 256, 0, stream>>>(flag, inp, hx, cx, Wq_i, Wk_i, Wv_i,
                                       Wq_c, Wk_c, Wv_c, Wf_c, bf_c, Wg_c, bg_c,
                                       W_ih, W_hh, b_ih, b_hh, W_read, W_write,
                                       off_f32(0), off_f32(2097152), off_f32(4194304),
                                       off_f32(6291456), off_f32(6307840));
  k_scoff<1><<<1024, 256, 0, stream>>>(flag, inp, hx, cx, Wq_i, Wk_i, Wv_i,
                                       Wq_c, Wk_c, Wv_c, Wf_c, bf_c, Wg_c, bg_c,
                                       W_ih, W_hh, b_ih, b_hh, W_read, W_write,
                                       off_b16(0), off_b16(2097152), off_b16(4194304),
                                       off_b16(6291456), off_b16(6307840));
}

// Round 5
// 616.734 us; speedup vs baseline: 1.1351x; 1.1351x over previous
//
#include <hip/hip_runtime.h>
#include <hip/hip_bf16.h>
#include <stdint.h>

typedef __hip_bfloat16 bf16;
typedef _Float16 half_t;
typedef __attribute__((ext_vector_type(8))) _Float16 half8;
typedef __attribute__((ext_vector_type(4))) float float4v;

// ---------------- threefry2x32 (exact JAX semantics) ----------------
struct TF2 { unsigned a, b; };
__host__ __device__ constexpr unsigned rotl32(unsigned v, int r) {
  return (v << r) | (v >> (32 - r));
}
__host__ __device__ constexpr TF2 tf2x32(unsigned k0, unsigned k1, unsigned x0, unsigned x1) {
  unsigned ks2 = k0 ^ k1 ^ 0x1BD11BDAu;
  x0 += k0; x1 += k1;
  const int ra[4] = {13, 15, 26, 6};
  const int rb[4] = {17, 29, 16, 24};
  for (int i = 0; i < 4; i++) { x0 += x1; x1 = rotl32(x1, ra[i]); x1 ^= x0; }
  x0 += k1; x1 += ks2 + 1u;
  for (int i = 0; i < 4; i++) { x0 += x1; x1 = rotl32(x1, rb[i]); x1 ^= x0; }
  x0 += ks2; x1 += k0 + 2u;
  for (int i = 0; i < 4; i++) { x0 += x1; x1 = rotl32(x1, ra[i]); x1 ^= x0; }
  x0 += k0; x1 += k1 + 3u;
  for (int i = 0; i < 4; i++) { x0 += x1; x1 = rotl32(x1, rb[i]); x1 ^= x0; }
  x0 += k1; x1 += ks2 + 4u;
  for (int i = 0; i < 4; i++) { x0 += x1; x1 = rotl32(x1, ra[i]); x1 ^= x0; }
  x0 += ks2; x1 += k0 + 5u;
  return TF2{x0, x1};
}
constexpr unsigned GK0 = tf2x32(0u, 0u, 0u, 12345u).a;
constexpr unsigned GK1 = tf2x32(0u, 0u, 0u, 12345u).b;

// JAX threefry_partitionable (default) 32-bit bits: counter (0, j), XOR-fold.
__device__ __forceinline__ float gumbel_at(unsigned j) {
  TF2 r = tf2x32(GK0, GK1, 0u, j);
  unsigned bits = r.a ^ r.b;
  float u = __uint_as_float((bits >> 9) | 0x3f800000u) - 1.0f;
  u = fmaxf(1.17549435e-38f, u + 1.17549435e-38f);
  return -logf(-logf(u));
}

__device__ __forceinline__ float sigm(float x) { return 1.0f / (1.0f + expf(-x)); }

// ---------------- ws (pre-split weights) layout, f16 element offsets ----------------
constexpr int GH  = 0;        // gates hi  [n=2048][k=256]
constexpr int GL  = 524288;   // gates lo
constexpr int WWH = 1048576;  // W_write hi [m*16+d][s=128]
constexpr int WWL = 1056768;  // W_write lo
constexpr int CQ  = 1064960;  // Wq_c  [col=128][k=128]
constexpr int CK  = 1081344;
constexpr int CV  = 1097728;
constexpr int CF  = 1114112;
constexpr int CG  = 1130496;
constexpr int WS_HALF_TOTAL = 1146880;
constexpr size_t WS_FLAG_OFF = (size_t)WS_HALF_TOTAL * 2;       // byte offset of flag
constexpr size_t WS_NEED     = WS_FLAG_OFF + 64;

// ---------------- dtype probe: bf16-decode of f32 data explodes ----------------
__global__ void k_detect(const void* inp, int* flag) {
  __shared__ int bad;
  if (threadIdx.x == 0) bad = 0;
  __syncthreads();
  const unsigned short* u = (const unsigned short*)inp;
  for (int i = threadIdx.x; i < 1024; i += 256) {
    float v = __uint_as_float(((unsigned)u[i]) << 16);
    if (!(fabsf(v) < 64.f)) atomicOr(&bad, 1);
  }
  __syncthreads();
  if (threadIdx.x == 0) *flag = bad ? 0 : 1;   // 0 = f32, 1 = bf16
}

// ---------------- one-time (per-call) weight split into ws ----------------
__global__ __launch_bounds__(256)
void k_wsplit(const float* __restrict__ W_ih, const float* __restrict__ W_hh,
              const float* __restrict__ W_write,
              const float* __restrict__ Wq_c, const float* __restrict__ Wk_c,
              const float* __restrict__ Wv_c, const float* __restrict__ Wf_c,
              const float* __restrict__ Wg_c, half_t* __restrict__ ws) {
  int i = blockIdx.x * 256 + threadIdx.x;
  if (i < 524288) {                         // gates: n=2048, k=256
    int n = i >> 8, k = i & 255;
    int m = n >> 9, g = n & 511;
    float w = (k < 128) ? W_ih[(m * 512 + g) * 128 + k]
                        : W_hh[(m * 512 + g) * 128 + (k - 128)];
    half_t h = (half_t)w;
    ws[GH + i] = h;
    ws[GL + i] = (half_t)(w - (float)h);
  } else if (i < 532480) {                  // W_write: [m*16+d][s]
    int j = i - 524288; int md = j >> 7, s = j & 127; int m = md >> 4, d = md & 15;
    float w = W_write[(m * 128 + s) * 16 + d];
    half_t h = (half_t)w;
    ws[WWH + j] = h;
    ws[WWL + j] = (half_t)(w - (float)h);
  } else if (i < 614400) {                  // comm mats, transposed [col][k]
    int j = i - 532480; int which = j >> 14, r = j & 16383;
    int col = r >> 7, k = r & 127;
    const float* Wsel = which == 0 ? Wq_c : which == 1 ? Wk_c :
                        which == 2 ? Wv_c : which == 3 ? Wf_c : Wg_c;
    ws[CQ + which * 16384 + r] = (half_t)Wsel[k * 128 + col];
  }
}

#define MFMA16(a, b, c) __builtin_amdgcn_mfma_f32_16x16x32_f16((a), (b), (c), 0, 0, 0)

// ============ MFMA fused SCOFF (f32 inputs): one block = 2 batches = 16 rows ============
__global__ __launch_bounds__(256)
void k_scoff_mfma(const int* __restrict__ flag, const half_t* __restrict__ wsp,
                  const float* __restrict__ inp, const float* __restrict__ hx,
                  const float* __restrict__ cx,
                  const float* __restrict__ Wq_i, const float* __restrict__ Wk_i,
                  const float* __restrict__ Wv_i,
                  const float* __restrict__ bf_c, const float* __restrict__ bg_c,
                  const float* __restrict__ b_ih, const float* __restrict__ b_hh,
                  const float* __restrict__ W_read,
                  float* __restrict__ out_hx, float* __restrict__ out_cx,
                  float* __restrict__ out_mask, float* __restrict__ out_bm,
                  float* __restrict__ out_ta)
{
  if (*flag != 0) return;

  const int t = threadIdx.x;
  const int n0 = blockIdx.x * 16, gbase = n0 * 128;
  const int lane = t & 63, wv = t >> 6;
  const int col15 = lane & 15, quad = lane >> 4;

  __shared__ __align__(16) float hxs[2048];
  __shared__ __align__(16) float cxs[2048];
  __shared__ __align__(16) float vsb[2048];        // vs, then bsum
  __shared__ float qsb[1088], kslb[1088];          // padded stride 68
  __shared__ __align__(16) half_t sXh[16 * 264];
  __shared__ __align__(16) half_t sXl[16 * 264];
  __shared__ __align__(16) half_t hth[16 * 520];
  __shared__ __align__(16) half_t htl[16 * 520];
  __shared__ __align__(16) half_t cts[16 * 512];
  __shared__ float wks[1024];
  __shared__ __align__(16) half_t hbF[16 * 136];
  __shared__ __align__(16) half_t oF[16 * 136];
  __shared__ __align__(16) half_t qcF[16 * 136];
  __shared__ __align__(16) half_t kcF[16 * 136];
  __shared__ __align__(16) half_t vcF[16 * 136];
  __shared__ float attb[512];
  __shared__ float hrs_[256];
  __shared__ float zbuf[64];
  __shared__ float m8_[16];
  __shared__ int   msh_[16];

  // ============ P0: stage hx, inp, cx ============
  for (int idx = t; idx < 512; idx += 256) {
    *reinterpret_cast<float4*>(&hxs[idx * 4]) =
        *reinterpret_cast<const float4*>(hx + gbase + idx * 4);
    *reinterpret_cast<float4*>(&cxs[idx * 4]) =
        *reinterpret_cast<const float4*>(cx + gbase + idx * 4);
  }
  {
    __shared__ __align__(16) float inps[2048];
    for (int idx = t; idx < 512; idx += 256)
      *reinterpret_cast<float4*>(&inps[idx * 4]) =
          *reinterpret_cast<const float4*>(inp + gbase + idx * 4);
    __syncthreads();

    // ============ P1a: qs/ksl/vs projections, h_read, X hx-part ============
    for (int idx = t; idx < 1024; idx += 256) {
      int k16 = idx >> 6, d = idx & 63;
      float aq = 0.f, ak = 0.f;
#pragma unroll 8
      for (int i = 0; i < 128; i++) {
        aq += hxs[k16 * 128 + i]  * Wq_i[i * 64 + d];
        ak += inps[k16 * 128 + i] * Wk_i[i * 64 + d];
      }
      qsb[k16 * 68 + d] = aq; kslb[k16 * 68 + d] = ak;
    }
    for (int idx = t; idx < 2048; idx += 256) {
      int n16 = idx >> 7, j = idx & 127;
      float a = 0.f;
#pragma unroll 8
      for (int i = 0; i < 128; i++) a += inps[n16 * 128 + i] * Wv_i[i * 128 + j];
      vsb[idx] = a;
    }
  }
  {
    int n16 = t >> 4, d = t & 15;
    float a = 0.f;
#pragma unroll 8
    for (int i = 0; i < 128; i++) a += hxs[n16 * 128 + i] * W_read[i * 16 + d];
    hrs_[t] = a;
  }
  for (int idx = t; idx < 2048; idx += 256) {   // X hx-part (k = 128..255)
    int r = idx >> 7, i = idx & 127;
    float v = hxs[r * 128 + i];
    half_t hh = (half_t)v;
    sXh[r * 264 + 128 + i] = hh;
    sXl[r * 264 + 128 + i] = (half_t)(v - (float)hh);
  }
  __syncthreads();

  // ============ P1b: scores, softmax, top-k, inp_use -> X ============
  if (t < 128) {
    int b2 = t >> 6, k = (t >> 3) & 7, n = t & 7;
    float sc = 0.f;
#pragma unroll
    for (int d = 0; d < 64; d++)
      sc += qsb[(b2 * 8 + k) * 68 + d] * kslb[(b2 * 8 + n) * 68 + d];
    attb[b2 * 72 + k * 9 + n] = sc * 0.125f;
  } else if (t < 144) {
    int u = t - 128, b2 = u >> 3, k = u & 7;
    attb[b2 * 72 + k * 9 + 8] = 0.f;
  }
  __syncthreads();
  if (t < 16) {
    int b2 = t >> 3, k = t & 7;
    float* row = &attb[b2 * 72 + k * 9];
    float mx = row[0];
    for (int n = 1; n < 9; n++) mx = fmaxf(mx, row[n]);
    float e[9], ssum = 0.f;
    for (int n = 0; n < 9; n++) { e[n] = expf(row[n] - mx); ssum += e[n]; }
    for (int n = 0; n < 9; n++) row[n] = e[n] / ssum;
  }
  __syncthreads();
  if (t < 2) {
    bool taken[8] = {};
    for (int dd = 0; dd < 3; dd++) {
      int bi = 0; float bv = -1e30f;
      for (int k = 0; k < 8; k++) {
        float v = attb[t * 72 + k * 9 + 0];
        if (!taken[k] && v > bv) { bv = v; bi = k; }
      }
      taken[bi] = true;
    }
    for (int k = 0; k < 8; k++) m8_[t * 8 + k] = taken[k] ? 0.f : 1.f;
  }
  __syncthreads();
  for (int idx = t; idx < 2048; idx += 256) {
    int n16 = idx >> 7, j = idx & 127, b2 = n16 >> 3, k = n16 & 7;
    float a = 0.f;
#pragma unroll
    for (int n = 0; n < 8; n++) a += attb[b2 * 72 + k * 9 + n] * vsb[(b2 * 8 + n) * 128 + j];
    half_t hh = (half_t)a;
    sXh[n16 * 264 + j] = hh;
    sXl[n16 * 264 + j] = (half_t)(a - (float)hh);
    out_mask[gbase + idx] = m8_[n16];
  }
  if (t < 16) out_bm[n0 + t] = m8_[t];
  __syncthreads();
  for (int idx = t; idx < 2048; idx += 256) vsb[idx] = b_ih[idx] + b_hh[idx]; // bsum
  __syncthreads();

  // ============ P2: gates GEMM via MFMA f16 3-pass + LSTM epilogue ============
  {
    float4v acc[32];
#pragma unroll
    for (int ct = 0; ct < 32; ct++) acc[ct] = (float4v){0.f, 0.f, 0.f, 0.f};
    const half_t* Ah = &sXh[col15 * 264 + quad * 8];
    const half_t* Al = &sXl[col15 * 264 + quad * 8];
    const half_t* Bh = wsp + GH + (size_t)(wv * 512 + col15) * 256 + quad * 8;
    const half_t* Bl = wsp + GL + (size_t)(wv * 512 + col15) * 256 + quad * 8;
    for (int ks = 0; ks < 8; ks++) {
      half8 ah = *reinterpret_cast<const half8*>(Ah + ks * 32);
      half8 al = *reinterpret_cast<const half8*>(Al + ks * 32);
#pragma unroll
      for (int ct = 0; ct < 32; ct++) {
        half8 bh = *reinterpret_cast<const half8*>(Bh + ct * 4096 + ks * 32);
        half8 bl = *reinterpret_cast<const half8*>(Bl + ct * 4096 + ks * 32);
        acc[ct] = MFMA16(ah, bh, acc[ct]);
        acc[ct] = MFMA16(ah, bl, acc[ct]);
        acc[ct] = MFMA16(al, bh, acc[ct]);
      }
    }
#pragma unroll
    for (int sh = 0; sh < 8; sh++) {
      int s = sh * 16 + col15;
      float bi = vsb[wv * 512 + s];
      float bf = vsb[wv * 512 + 128 + s];
      float bg = vsb[wv * 512 + 256 + s];
      float bo = vsb[wv * 512 + 384 + s];
#pragma unroll
      for (int rg = 0; rg < 4; rg++) {
        int row = quad * 4 + rg;
        float iv = acc[sh][rg] + bi;
        float fv = acc[8 + sh][rg] + bf;
        float gv = acc[16 + sh][rg] + bg;
        float ov = acc[24 + sh][rg] + bo;
        float cc = sigm(fv) * cxs[row * 128 + s] + sigm(iv) * tanhf(gv);
        float hh = sigm(ov) * tanhf(cc);
        half_t hhi = (half_t)hh;
        hth[row * 520 + wv * 128 + s] = hhi;
        htl[row * 520 + wv * 128 + s] = (half_t)(hh - (float)hhi);
        cts[row * 512 + wv * 128 + s] = (half_t)cc;
      }
    }
  }
  __syncthreads();

  // ============ P3: write-key MFMA, logits+gumbel argmax, cx out, hb ============
  {
    float4v wacc = (float4v){0.f, 0.f, 0.f, 0.f};
    const half_t* Wh = wsp + WWH + (wv * 16 + col15) * 128 + quad * 8;
    const half_t* Wl = wsp + WWL + (wv * 16 + col15) * 128 + quad * 8;
    const half_t* Hh = &hth[col15 * 520 + wv * 128 + quad * 8];
    const half_t* Hl = &htl[col15 * 520 + wv * 128 + quad * 8];
#pragma unroll
    for (int ks = 0; ks < 4; ks++) {
      half8 ah = *reinterpret_cast<const half8*>(Hh + ks * 32);
      half8 al = *reinterpret_cast<const half8*>(Hl + ks * 32);
      half8 bh = *reinterpret_cast<const half8*>(Wh + ks * 32);
      half8 bl = *reinterpret_cast<const half8*>(Wl + ks * 32);
      wacc = MFMA16(ah, bh, wacc);
      wacc = MFMA16(ah, bl, wacc);
      wacc = MFMA16(al, bh, wacc);
    }
#pragma unroll
    for (int rg = 0; rg < 4; rg++)
      wks[wv * 256 + (quad * 4 + rg) * 16 + col15] = wacc[rg];
  }
  __syncthreads();
  if (t < 64) {
    int row = t >> 2, mm = t & 3;
    float lg = 0.f;
#pragma unroll
    for (int d = 0; d < 16; d++) lg += hrs_[row * 16 + d] * wks[mm * 256 + row * 16 + d];
    zbuf[t] = lg + gumbel_at((unsigned)((n0 + row) * 4 + mm));
  }
  __syncthreads();
  if (t < 16) {
    int ms = 0; float best = zbuf[t * 4];
#pragma unroll
    for (int m = 1; m < 4; m++)
      if (zbuf[t * 4 + m] > best) { best = zbuf[t * 4 + m]; ms = m; }
    msh_[t] = ms;
#pragma unroll
    for (int m = 0; m < 4; m++) out_ta[(n0 + t) * 4 + m] = (m == ms) ? 1.0f : 0.0f;
  }
  __syncthreads();
  for (int idx = t; idx < 2048; idx += 256) {
    int r = idx >> 7, s = idx & 127;
    float cv = (float)cts[r * 512 + msh_[r] * 128 + s];
    out_cx[gbase + idx] = (m8_[r] != 0.f) ? cv : cxs[idx];
    hbF[r * 136 + s] = hth[r * 520 + msh_[r] * 128 + s];
  }
  __syncthreads();

  // ============ P4a: comm q/k/v projections (single-pass f16 MFMA) ============
  if (wv < 3) {
    float4v pacc[8];
#pragma unroll
    for (int ct = 0; ct < 8; ct++) pacc[ct] = (float4v){0.f, 0.f, 0.f, 0.f};
    const half_t* Bp = wsp + CQ + wv * 16384 + col15 * 128 + quad * 8;
    const half_t* Ap = &hbF[col15 * 136 + quad * 8];
#pragma unroll
    for (int ks = 0; ks < 4; ks++) {
      half8 a = *reinterpret_cast<const half8*>(Ap + ks * 32);
#pragma unroll
      for (int ct = 0; ct < 8; ct++) {
        half8 b = *reinterpret_cast<const half8*>(Bp + ct * 2048 + ks * 32);
        pacc[ct] = MFMA16(a, b, pacc[ct]);
      }
    }
    half_t* dst = (wv == 0) ? qcF : (wv == 1) ? kcF : vcF;
#pragma unroll
    for (int ct = 0; ct < 8; ct++)
#pragma unroll
      for (int rg = 0; rg < 4; rg++)
        dst[(quad * 4 + rg) * 136 + ct * 16 + col15] = (half_t)pacc[ct][rg];
  }
  __syncthreads();

  // ============ P4b: scores + softmax ============
  if (t < 64) {
    int b2 = t >> 5, h = (t >> 3) & 3, q = t & 7;
    float sc[8];
#pragma unroll
    for (int kq = 0; kq < 8; kq++) {
      float a = 0.f;
#pragma unroll
      for (int d = 0; d < 32; d++)
        a += (float)qcF[(b2 * 8 + q) * 136 + h * 32 + d] *
             (float)kcF[(b2 * 8 + kq) * 136 + h * 32 + d];
      sc[kq] = a * 0.17677669529663688110f;
    }
    float mx = sc[0];
#pragma unroll
    for (int kq = 1; kq < 8; kq++) mx = fmaxf(mx, sc[kq]);
    float e[8], ssum = 0.f;
#pragma unroll
    for (int kq = 0; kq < 8; kq++) { e[kq] = expf(sc[kq] - mx); ssum += e[kq]; }
#pragma unroll
    for (int kq = 0; kq < 8; kq++)
      attb[((b2 * 4 + h) * 8 + q) * 8 + kq] = e[kq] / ssum;
  }
  __syncthreads();

  // ============ P4c: o = catt @ vc ============
  for (int idx = t; idx < 2048; idx += 256) {
    int r = idx >> 7, cn = idx & 127, b2 = r >> 3, q = r & 7, h = cn >> 5;
    float a = 0.f;
#pragma unroll
    for (int kq = 0; kq < 8; kq++)
      a += attb[((b2 * 4 + h) * 8 + q) * 8 + kq] * (float)vcF[(b2 * 8 + kq) * 136 + cn];
    oF[r * 136 + cn] = (half_t)a;
  }
  __syncthreads();

  // ============ P4d: comm gates MFMA + final blend ============
  {
    float4v fa[2], ga[2];
#pragma unroll
    for (int tt = 0; tt < 2; tt++) {
      fa[tt] = (float4v){0.f, 0.f, 0.f, 0.f};
      ga[tt] = (float4v){0.f, 0.f, 0.f, 0.f};
    }
    const half_t* Ao = &oF[col15 * 136 + quad * 8];
    const half_t* Bf = wsp + CF + (wv * 32 + col15) * 128 + quad * 8;
    const half_t* Bg = wsp + CG + (wv * 32 + col15) * 128 + quad * 8;
#pragma unroll
    for (int ks = 0; ks < 4; ks++) {
      half8 a = *reinterpret_cast<const half8*>(Ao + ks * 32);
#pragma unroll
      for (int tt = 0; tt < 2; tt++) {
        half8 bf = *reinterpret_cast<const half8*>(Bf + tt * 2048 + ks * 32);
        half8 bg = *reinterpret_cast<const half8*>(Bg + tt * 2048 + ks * 32);
        fa[tt] = MFMA16(a, bf, fa[tt]);
        ga[tt] = MFMA16(a, bg, ga[tt]);
      }
    }
#pragma unroll
    for (int tt = 0; tt < 2; tt++) {
      int col = wv * 32 + tt * 16 + col15;
      float bfv = bf_c[col], bgv = bg_c[col];
#pragma unroll
      for (int rg = 0; rg < 4; rg++) {
        int row = quad * 4 + rg;
        float af = fa[tt][rg] + bfv;
        float ag = ga[tt][rg] + bgv;
        float comm = sigm(ag) * tanhf(af);
        float hb = (float)hth[row * 520 + msh_[row] * 128 + col] +
                   (float)htl[row * 520 + msh_[row] * 128 + col];
        float hv = (m8_[row] != 0.f) ? (hb + comm)
                                     : hx[(size_t)(n0 + row) * 128 + col];
        out_hx[(size_t)(n0 + row) * 128 + col] = hv;
      }
    }
  }
}

// ================= fallback: round-4 VALU kernel (f32 / bf16) =================
template<int MODE> struct IO;
template<> struct IO<0> {
  static __device__ __forceinline__ float ld(const void* p, int i) { return ((const float*)p)[i]; }
  static __device__ __forceinline__ void st(void* p, int i, float v) { ((float*)p)[i] = v; }
};
template<> struct IO<1> {
  static __device__ __forceinline__ float ld(const void* p, int i) {
    return __bfloat162float(((const bf16*)p)[i]);
  }
  static __device__ __forceinline__ void st(void* p, int i, float v) {
    ((bf16*)p)[i] = __float2bfloat16(v);
  }
};

template<int MODE>
__global__ __launch_bounds__(256, 2)
void k_scoff(const int* __restrict__ flag,
             const void* __restrict__ inp, const void* __restrict__ hx,
             const void* __restrict__ cx,
             const void* __restrict__ Wq_i, const void* __restrict__ Wk_i,
             const void* __restrict__ Wv_i,
             const void* __restrict__ Wq_c, const void* __restrict__ Wk_c,
             const void* __restrict__ Wv_c, const void* __restrict__ Wf_c,
             const void* __restrict__ bf_c, const void* __restrict__ Wg_c,
             const void* __restrict__ bg_c,
             const void* __restrict__ W_ih, const void* __restrict__ W_hh,
             const void* __restrict__ b_ih, const void* __restrict__ b_hh,
             const void* __restrict__ W_read, const void* __restrict__ W_write,
             void* __restrict__ out_hx, void* __restrict__ out_cx,
             void* __restrict__ out_mask, void* __restrict__ out_bm,
             void* __restrict__ out_ta)
{
  if (*flag != MODE) return;

  const int t  = threadIdx.x;
  const int n0 = blockIdx.x * 16;
  const int gbase = n0 * 128;

  __shared__ float inps_os[2048];
  __shared__ float As[4096];
  __shared__ float Bs[8320];
  __shared__ float attbuf[512];
  __shared__ float hrs[256];
  __shared__ float m8[16];
  __shared__ int   msh[16];

  float* const qs  = Bs;
  float* const ksl = Bs + 1024;
  float* const vs  = Bs + 2048;
  float* const hxs = Bs + 4096;

  if constexpr (MODE == 1) {
    const unsigned* hx32 = (const unsigned*)((const bf16*)hx + gbase);
    const unsigned* in32 = (const unsigned*)((const bf16*)inp + gbase);
    for (int idx = t; idx < 1024; idx += 256) {
      unsigned wh = hx32[idx], wi = in32[idx];
      hxs[2 * idx]         = __uint_as_float(wh << 16);
      hxs[2 * idx + 1]     = __uint_as_float(wh & 0xffff0000u);
      inps_os[2 * idx]     = __uint_as_float(wi << 16);
      inps_os[2 * idx + 1] = __uint_as_float(wi & 0xffff0000u);
    }
  } else {
    const float* hxf = (const float*)hx + gbase;
    const float* inf_ = (const float*)inp + gbase;
    for (int idx = t; idx < 512; idx += 256) {
      *reinterpret_cast<float4*>(&hxs[idx * 4]) =
          *reinterpret_cast<const float4*>(hxf + idx * 4);
      *reinterpret_cast<float4*>(&inps_os[idx * 4]) =
          *reinterpret_cast<const float4*>(inf_ + idx * 4);
    }
  }
  __syncthreads();

  for (int idx = t; idx < 1024; idx += 256) {
    int k16 = idx >> 6, d = idx & 63;
    float aq = 0.f, ak = 0.f;
#pragma unroll 8
    for (int i = 0; i < 128; i++) {
      aq += hxs[k16 * 128 + i]     * IO<MODE>::ld(Wq_i, i * 64 + d);
      ak += inps_os[k16 * 128 + i] * IO<MODE>::ld(Wk_i, i * 64 + d);
    }
    qs[idx] = aq; ksl[idx] = ak;
  }
  for (int idx = t; idx < 2048; idx += 256) {
    int n16 = idx >> 7, j = idx & 127;
    float a = 0.f;
#pragma unroll 8
    for (int i = 0; i < 128; i++) a += inps_os[n16 * 128 + i] * IO<MODE>::ld(Wv_i, i * 128 + j);
    vs[idx] = a;
  }
  for (int idx = t; idx < 2048; idx += 256) {
    int i = idx >> 4, r = idx & 15;
    As[(128 + i) * 16 + r] = hxs[r * 128 + i];
  }
  {
    int n16 = t >> 4, d = t & 15;
    float a = 0.f;
#pragma unroll 8
    for (int i = 0; i < 128; i++) a += hxs[n16 * 128 + i] * IO<MODE>::ld(W_read, i * 16 + d);
    hrs[t] = a;
  }
  __syncthreads();

  if (t < 128) {
    int b2 = t >> 6, k = (t >> 3) & 7, n = t & 7;
    float sc = 0.f;
#pragma unroll
    for (int d = 0; d < 64; d++) sc += qs[(b2 * 8 + k) * 64 + d] * ksl[(b2 * 8 + n) * 64 + d];
    attbuf[b2 * 72 + k * 9 + n] = sc * 0.125f;
  } else if (t < 144) {
    int u = t - 128, b2 = u >> 3, k = u & 7;
    attbuf[b2 * 72 + k * 9 + 8] = 0.f;
  }
  __syncthreads();
  if (t < 16) {
    int b2 = t >> 3, k = t & 7;
    float* row = &attbuf[b2 * 72 + k * 9];
    float mx = row[0];
    for (int n = 1; n < 9; n++) mx = fmaxf(mx, row[n]);
    float e[9], ssum = 0.f;
    for (int n = 0; n < 9; n++) { e[n] = expf(row[n] - mx); ssum += e[n]; }
    for (int n = 0; n < 9; n++) row[n] = e[n] / ssum;
  }
  __syncthreads();
  if (t < 2) {
    bool taken[8] = {};
    for (int dd = 0; dd < 3; dd++) {
      int bi = 0; float bv = -1e30f;
      for (int k = 0; k < 8; k++) {
        float v = attbuf[t * 72 + k * 9 + 0];
        if (!taken[k] && v > bv) { bv = v; bi = k; }
      }
      taken[bi] = true;
    }
    for (int k = 0; k < 8; k++) m8[t * 8 + k] = taken[k] ? 0.f : 1.f;
  }
  __syncthreads();
  for (int idx = t; idx < 2048; idx += 256) {
    int n16 = idx >> 7, j = idx & 127, b2 = n16 >> 3, k = n16 & 7;
    float a = 0.f;
#pragma unroll
    for (int n = 0; n < 8; n++) a += attbuf[b2 * 72 + k * 9 + n] * vs[(b2 * 8 + n) * 128 + j];
    As[j * 16 + n16] = a;
    IO<MODE>::st(out_mask, gbase + idx, m8[n16]);
  }
  if (t < 16) IO<MODE>::st(out_bm, n0 + t, m8[t]);
  __syncthreads();

  const int s = t & 127, rg = t >> 7;
  float cvals[8];
#pragma unroll
  for (int j = 0; j < 8; j++) cvals[j] = IO<MODE>::ld(cx, (n0 + rg * 8 + j) * 128 + s);

  float ht[8][4], ct[8][4];
  const int sq = t >> 1, hf = t & 1;

#pragma unroll
  for (int m = 0; m < 4; m++) {
    float acc[8][4];
#pragma unroll
    for (int j = 0; j < 8; j++)
#pragma unroll
      for (int q = 0; q < 4; q++) acc[j][q] = 0.f;

    for (int kc = 0; kc < 256; kc += 16) {
      __syncthreads();
      {
        const int kb = (kc & 127) + hf * 8;
        float e[4][8];
        if constexpr (MODE == 1) {
          const bf16* Wsrc = (const bf16*)((kc < 128) ? W_ih : W_hh);
          uint4 wq[4];
#pragma unroll
          for (int q = 0; q < 4; q++)
            wq[q] = *reinterpret_cast<const uint4*>(Wsrc + ((m * 512 + q * 128 + sq) << 7) + kb);
#pragma unroll
          for (int q = 0; q < 4; q++) {
            unsigned w0 = wq[q].x, w1 = wq[q].y, w2 = wq[q].z, w3 = wq[q].w;
            e[q][0] = __uint_as_float(w0 << 16); e[q][1] = __uint_as_float(w0 & 0xffff0000u);
            e[q][2] = __uint_as_float(w1 << 16); e[q][3] = __uint_as_float(w1 & 0xffff0000u);
            e[q][4] = __uint_as_float(w2 << 16); e[q][5] = __uint_as_float(w2 & 0xffff0000u);
            e[q][6] = __uint_as_float(w3 << 16); e[q][7] = __uint_as_float(w3 & 0xffff0000u);
          }
        } else {
          const float* Wsrc = (const float*)((kc < 128) ? W_ih : W_hh);
#pragma unroll
          for (int q = 0; q < 4; q++) {
            const float* rowp = Wsrc + ((m * 512 + q * 128 + sq) << 7) + kb;
            float4 lo = *reinterpret_cast<const float4*>(rowp);
            float4 hi = *reinterpret_cast<const float4*>(rowp + 4);
            e[q][0] = lo.x; e[q][1] = lo.y; e[q][2] = lo.z; e[q][3] = lo.w;
            e[q][4] = hi.x; e[q][5] = hi.y; e[q][6] = hi.z; e[q][7] = hi.w;
          }
        }
#pragma unroll
        for (int c = 0; c < 8; c++) {
          float4 v; v.x = e[0][c]; v.y = e[1][c]; v.z = e[2][c]; v.w = e[3][c];
          *reinterpret_cast<float4*>(&Bs[(hf * 8 + c) * 520 + sq * 4]) = v;
        }
      }
      __syncthreads();
#pragma unroll
      for (int kk = 0; kk < 16; kk++) {
        const float4* ap = reinterpret_cast<const float4*>(&As[(kc + kk) * 16 + rg * 8]);
        float4 a0 = ap[0], a1 = ap[1];
        float4 bb = *reinterpret_cast<const float4*>(&Bs[kk * 520 + s * 4]);
        float av[8] = {a0.x, a0.y, a0.z, a0.w, a1.x, a1.y, a1.z, a1.w};
#pragma unroll
        for (int j = 0; j < 8; j++) {
          acc[j][0] += av[j] * bb.x;
          acc[j][1] += av[j] * bb.y;
          acc[j][2] += av[j] * bb.z;
          acc[j][3] += av[j] * bb.w;
        }
      }
    }
    float badd[4];
#pragma unroll
    for (int q = 0; q < 4; q++)
      badd[q] = IO<MODE>::ld(b_ih, m * 512 + q * 128 + s) +
                IO<MODE>::ld(b_hh, m * 512 + q * 128 + s);
#pragma unroll
    for (int j = 0; j < 8; j++) {
      float ig = acc[j][0] + badd[0];
      float fg = acc[j][1] + badd[1];
      float gg = acc[j][2] + badd[2];
      float og = acc[j][3] + badd[3];
      float c_t = sigm(fg) * cvals[j] + sigm(ig) * tanhf(gg);
      float h_t = sigm(og) * tanhf(c_t);
      ct[j][m] = c_t; ht[j][m] = h_t;
    }
  }

  __syncthreads();
#pragma unroll
  for (int j = 0; j < 8; j++) {
    int r = rg * 8 + j;
#pragma unroll
    for (int m = 0; m < 4; m++) Bs[r * 520 + m * 128 + s] = ht[j][m];
  }
  __syncthreads();
  {
    const int row = t >> 4, d = t & 15;
    const float hr = hrs[t];
    float lg[4];
#pragma unroll
    for (int m = 0; m < 4; m++) {
      float wk = 0.f;
#pragma unroll 8
      for (int ss = 0; ss < 128; ss++)
        wk += Bs[row * 520 + m * 128 + ss] * IO<MODE>::ld(W_write, (m * 128 + ss) * 16 + d);
      float p = hr * wk;
      p += __shfl_xor(p, 1, 64);
      p += __shfl_xor(p, 2, 64);
      p += __shfl_xor(p, 4, 64);
      p += __shfl_xor(p, 8, 64);
      lg[m] = p;
    }
    if (d == 0) {
      const int n = n0 + row;
      float z[4];
#pragma unroll
      for (int m = 0; m < 4; m++) z[m] = lg[m] + gumbel_at((unsigned)(n * 4 + m));
      int ms = 0; float best = z[0];
#pragma unroll
      for (int m = 1; m < 4; m++) if (z[m] > best) { best = z[m]; ms = m; }
      msh[row] = ms;
#pragma unroll
      for (int m = 0; m < 4; m++)
        IO<MODE>::st(out_ta, n * 4 + m, (m == ms) ? 1.0f : 0.0f);
    }
  }
  __syncthreads();
#pragma unroll
  for (int j = 0; j < 8; j++) {
    int r = rg * 8 + j;
    int ms = msh[r];
    float cv = ct[j][0];
    if (ms == 1) cv = ct[j][1];
    else if (ms == 2) cv = ct[j][2];
    else if (ms == 3) cv = ct[j][3];
    float co = (m8[r] != 0.f) ? cv : cvals[j];
    IO<MODE>::st(out_cx, (n0 + r) * 128 + s, co);
  }

  __syncthreads();
  for (int idx = t; idx < 2048; idx += 256) {
    int r = idx >> 7, col = idx & 127;
    As[idx] = Bs[r * 520 + msh[r] * 128 + col];
  }
  __syncthreads();
  for (int idx = t; idx < 2048; idx += 256) {
    int r = idx >> 7, col = idx & 127;
    float aq = 0.f, ak = 0.f, av = 0.f;
#pragma unroll 8
    for (int i = 0; i < 128; i++) {
      float h = As[r * 128 + i];
      aq += h * IO<MODE>::ld(Wq_c, i * 128 + col);
      ak += h * IO<MODE>::ld(Wk_c, i * 128 + col);
      av += h * IO<MODE>::ld(Wv_c, i * 128 + col);
    }
    Bs[idx] = aq; Bs[2048 + idx] = ak; Bs[4096 + idx] = av;
  }
  __syncthreads();
  if (t < 64) {
    int b2 = t >> 5, h = (t >> 3) & 3, q = t & 7;
    float sc[8];
#pragma unroll
    for (int kq = 0; kq < 8; kq++) {
      float a = 0.f;
#pragma unroll
      for (int d = 0; d < 32; d++)
        a += Bs[(b2 * 8 + q) * 128 + h * 32 + d] * Bs[2048 + (b2 * 8 + kq) * 128 + h * 32 + d];
      sc[kq] = a * 0.17677669529663688110f;
    }
    float mx = sc[0];
#pragma unroll
    for (int kq = 1; kq < 8; kq++) mx = fmaxf(mx, sc[kq]);
    float e[8], ssum = 0.f;
#pragma unroll
    for (int kq = 0; kq < 8; kq++) { e[kq] = expf(sc[kq] - mx); ssum += e[kq]; }
#pragma unroll
    for (int kq = 0; kq < 8; kq++)
      attbuf[((b2 * 4 + h) * 8 + q) * 8 + kq] = e[kq] / ssum;
  }
  __syncthreads();
  for (int idx = t; idx < 2048; idx += 256) {
    int r = idx >> 7, col = idx & 127, b2 = r >> 3, q = r & 7, h = col >> 5;
    float a = 0.f;
#pragma unroll
    for (int kq = 0; kq < 8; kq++)
      a += attbuf[((b2 * 4 + h) * 8 + q) * 8 + kq] * Bs[4096 + (b2 * 8 + kq) * 128 + col];
    inps_os[idx] = a;
  }
  __syncthreads();
  for (int idx = t; idx < 2048; idx += 256) {
    int r = idx >> 7, col = idx & 127;
    float af = IO<MODE>::ld(bf_c, col);
    float ag = IO<MODE>::ld(bg_c, col);
#pragma unroll 8
    for (int d = 0; d < 128; d++) {
      float o = inps_os[r * 128 + d];
      af += o * IO<MODE>::ld(Wf_c, d * 128 + col);
      ag += o * IO<MODE>::ld(Wg_c, d * 128 + col);
    }
    float comm = sigm(ag) * tanhf(af);
    float hv = (m8[r] != 0.f) ? (As[r * 128 + col] + comm)
                              : IO<MODE>::ld(hx, gbase + idx);
    IO<MODE>::st(out_hx, gbase + idx, hv);
  }
}

// ============================ launch ============================
extern "C" void kernel_launch(void* const* d_in, const int* in_sizes, int n_in,
                              void* d_out, int out_size, void* d_ws, size_t ws_size,
                              hipStream_t stream) {
  const void* inp     = d_in[0];
  const void* hx      = d_in[1];
  const void* cx      = d_in[2];
  const void* Wq_i    = d_in[3];
  const void* Wk_i    = d_in[4];
  const void* Wv_i    = d_in[5];
  const void* Wq_c    = d_in[6];
  const void* Wk_c    = d_in[7];
  const void* Wv_c    = d_in[8];
  const void* Wf_c    = d_in[9];
  const void* bf_c    = d_in[10];
  const void* Wg_c    = d_in[11];
  const void* bg_c    = d_in[12];
  const void* W_ih    = d_in[13];
  const void* W_hh    = d_in[14];
  const void* b_ih    = d_in[15];
  const void* b_hh    = d_in[16];
  const void* W_read  = d_in[17];
  const void* W_write = d_in[18];

  auto off_f32 = [&](int e) -> float* { return (float*)d_out + e; };
  auto off_b16 = [&](int e) -> void* { return (void*)((bf16*)d_out + e); };

  if (ws_size >= WS_NEED) {
    half_t* wsp = (half_t*)d_ws;
    int* flag = (int*)((char*)d_ws + WS_FLAG_OFF);
    k_detect<<<1, 256, 0, stream>>>(inp, flag);
    k_wsplit<<<2400, 256, 0, stream>>>((const float*)W_ih, (const float*)W_hh,
                                       (const float*)W_write,
                                       (const float*)Wq_c, (const float*)Wk_c,
                                       (const float*)Wv_c, (const float*)Wf_c,
                                       (const float*)Wg_c, wsp);
    k_scoff_mfma<<<1024, 256, 0, stream>>>(flag, wsp,
        (const float*)inp, (const float*)hx, (const float*)cx,
        (const float*)Wq_i, (const float*)Wk_i, (const float*)Wv_i,
        (const float*)bf_c, (const float*)bg_c,
        (const float*)b_ih, (const float*)b_hh, (const float*)W_read,
        off_f32(0), off_f32(2097152), off_f32(4194304),
        off_f32(6291456), off_f32(6307840));
    k_scoff<1><<<1024, 256, 0, stream>>>(flag, inp, hx, cx, Wq_i, Wk_i, Wv_i,
                                         Wq_c, Wk_c, Wv_c, Wf_c, bf_c, Wg_c, bg_c,
                                         W_ih, W_hh, b_ih, b_hh, W_read, W_write,
                                         off_b16(0), off_b16(2097152), off_b16(4194304),
                                         off_b16(6291456), off_b16(6307840));
  } else {
    int* flag = (int*)d_ws;
    k_detect<<<1, 256, 0, stream>>>(inp, flag);
    k_scoff<0><<<1024, 256, 0, stream>>>(flag, inp, hx, cx, Wq_i, Wk_i, Wv_i,
                                         Wq_c, Wk_c, Wv_c, Wf_c, bf_c, Wg_c, bg_c,
                                         W_ih, W_hh, b_ih, b_hh, W_read, W_write,
                                         (void*)off_f32(0), (void*)off_f32(2097152),
                                         (void*)off_f32(4194304), (void*)off_f32(6291456),
                                         (void*)off_f32(6307840));
    k_scoff<1><<<1024, 256, 0, stream>>>(flag, inp, hx, cx, Wq_i, Wk_i, Wv_i,
                                         Wq_c, Wk_c, Wv_c, Wf_c, bf_c, Wg_c, bg_c,
                                         W_ih, W_hh, b_ih, b_hh, W_read, W_write,
                                         off_b16(0), off_b16(2097152), off_b16(4194304),
                                         off_b16(6291456), off_b16(6307840));
  }
}

// Round 6
// 367.295 us; speedup vs baseline: 1.9060x; 1.6791x over previous
//
#include <hip/hip_runtime.h>
#include <hip/hip_bf16.h>
#include <stdint.h>

typedef __hip_bfloat16 bf16;
typedef _Float16 half_t;
typedef __attribute__((ext_vector_type(8))) _Float16 half8;
typedef __attribute__((ext_vector_type(4))) float float4v;

// ---------------- threefry2x32 (exact JAX semantics) ----------------
struct TF2 { unsigned a, b; };
__host__ __device__ constexpr unsigned rotl32(unsigned v, int r) {
  return (v << r) | (v >> (32 - r));
}
__host__ __device__ constexpr TF2 tf2x32(unsigned k0, unsigned k1, unsigned x0, unsigned x1) {
  unsigned ks2 = k0 ^ k1 ^ 0x1BD11BDAu;
  x0 += k0; x1 += k1;
  const int ra[4] = {13, 15, 26, 6};
  const int rb[4] = {17, 29, 16, 24};
  for (int i = 0; i < 4; i++) { x0 += x1; x1 = rotl32(x1, ra[i]); x1 ^= x0; }
  x0 += k1; x1 += ks2 + 1u;
  for (int i = 0; i < 4; i++) { x0 += x1; x1 = rotl32(x1, rb[i]); x1 ^= x0; }
  x0 += ks2; x1 += k0 + 2u;
  for (int i = 0; i < 4; i++) { x0 += x1; x1 = rotl32(x1, ra[i]); x1 ^= x0; }
  x0 += k0; x1 += k1 + 3u;
  for (int i = 0; i < 4; i++) { x0 += x1; x1 = rotl32(x1, rb[i]); x1 ^= x0; }
  x0 += k1; x1 += ks2 + 4u;
  for (int i = 0; i < 4; i++) { x0 += x1; x1 = rotl32(x1, ra[i]); x1 ^= x0; }
  x0 += ks2; x1 += k0 + 5u;
  return TF2{x0, x1};
}
constexpr unsigned GK0 = tf2x32(0u, 0u, 0u, 12345u).a;
constexpr unsigned GK1 = tf2x32(0u, 0u, 0u, 12345u).b;

// JAX threefry_partitionable (default) 32-bit bits: counter (0, j), XOR-fold.
__device__ __forceinline__ float gumbel_at(unsigned j) {
  TF2 r = tf2x32(GK0, GK1, 0u, j);
  unsigned bits = r.a ^ r.b;
  float u = __uint_as_float((bits >> 9) | 0x3f800000u) - 1.0f;
  u = fmaxf(1.17549435e-38f, u + 1.17549435e-38f);
  return -logf(-logf(u));
}

__device__ __forceinline__ float sigm(float x) { return 1.0f / (1.0f + expf(-x)); }

#define MFMA16(a, b, c) __builtin_amdgcn_mfma_f32_16x16x32_f16((a), (b), (c), 0, 0, 0)

// ================= tier-2 (round-5 monolith) ws layout =================
constexpr int GH  = 0;
constexpr int GL  = 524288;
constexpr int WWH = 1048576;
constexpr int WWL = 1056768;
constexpr int CQ  = 1064960;
constexpr int CF  = 1114112;
constexpr int CG  = 1130496;
constexpr int WS_HALF_TOTAL = 1146880;
constexpr size_t WS_FLAG_OFF = (size_t)WS_HALF_TOTAL * 2;
constexpr size_t WS_NEED     = WS_FLAG_OFF + 64;

// ================= tier-1 (split path) ws layout, half element offsets =====
constexpr size_t F_GH  = 0;          // swizzled gates hi: [m][nt32][ks8][lane64][8]
constexpr size_t F_GL  = 524288;
constexpr size_t F_WWH = 1048576;    // W_write hi [m*16+d][s]
constexpr size_t F_WWL = 1056768;
constexpr size_t F_CQ  = 1064960;    // 5 × 16384 (q,k,v,f,g) [col][k]
constexpr size_t F_XH  = 1146880;    // X frag: [rt1024][ks8][lane64][8]
constexpr size_t F_XL  = 5341184;
constexpr size_t F_HB  = 9535488;    // hb plain [row][s] f16
constexpr size_t F_END = 11632640;   // halfs
constexpr size_t G_HREAD = 0;        // f32 idx in f32 region
constexpr size_t G_MASK8 = 262144;
constexpr size_t G_FLAG  = 278528;
constexpr size_t WS2_NEED = F_END * 2 + (G_FLAG + 16) * 4;

// ---------------- dtype probe: bf16-decode of f32 data explodes ----------------
__global__ void k_detect(const void* inp, int* flag) {
  __shared__ int bad;
  if (threadIdx.x == 0) bad = 0;
  __syncthreads();
  const unsigned short* u = (const unsigned short*)inp;
  for (int i = threadIdx.x; i < 1024; i += 256) {
    float v = __uint_as_float(((unsigned)u[i]) << 16);
    if (!(fabsf(v) < 64.f)) atomicOr(&bad, 1);
  }
  __syncthreads();
  if (threadIdx.x == 0) *flag = bad ? 0 : 1;   // 0 = f32, 1 = bf16
}

// ================= tier-1 weight split (frag-swizzled gates) =================
__global__ __launch_bounds__(256)
void k_wsplit2(const int* __restrict__ flag,
               const float* __restrict__ W_ih, const float* __restrict__ W_hh,
               const float* __restrict__ W_write,
               const float* __restrict__ Wq_c, const float* __restrict__ Wk_c,
               const float* __restrict__ Wv_c, const float* __restrict__ Wf_c,
               const float* __restrict__ Wg_c, half_t* __restrict__ ws) {
  if (*flag != 0) return;
  int tid = blockIdx.x * 256 + threadIdx.x;
  if (tid < 65536) {                 // gates B-frags: unit = (m,nt,ks,lane)
    int m = tid >> 14, nt = (tid >> 9) & 31, ks = (tid >> 6) & 7, lane = tid & 63;
    int n = m * 512 + nt * 16 + (lane & 15);
    int kb = ks * 32 + (lane >> 4) * 8;
    half8 hi, lo;
#pragma unroll
    for (int j = 0; j < 8; j++) {
      int k = kb + j;
      float w = (k < 128) ? W_ih[n * 128 + k] : W_hh[n * 128 + (k - 128)];
      half_t h = (half_t)w;
      hi[j] = h; lo[j] = (half_t)(w - (float)h);
    }
    *reinterpret_cast<half8*>(ws + F_GH + (size_t)tid * 8) = hi;
    *reinterpret_cast<half8*>(ws + F_GL + (size_t)tid * 8) = lo;
  } else if (tid < 73728) {          // W_write: [m*16+d][s]
    int j = tid - 65536; int md = j >> 7, s = j & 127; int m = md >> 4, d = md & 15;
    float w = W_write[(m * 128 + s) * 16 + d];
    half_t h = (half_t)w;
    ws[F_WWH + j] = h;
    ws[F_WWL + j] = (half_t)(w - (float)h);
  } else if (tid < 83968) {          // comm mats transposed [col][k], half8 units
    int u = tid - 73728;
    int which = u >> 11, r8 = u & 2047;
    int col = r8 >> 4, k8 = r8 & 15;
    const float* Wsel = which == 0 ? Wq_c : which == 1 ? Wk_c :
                        which == 2 ? Wv_c : which == 3 ? Wf_c : Wg_c;
    half8 v;
#pragma unroll
    for (int j = 0; j < 8; j++) v[j] = (half_t)Wsel[(k8 * 8 + j) * 128 + col];
    *reinterpret_cast<half8*>(ws + F_CQ + (size_t)which * 16384 + col * 128 + k8 * 8) = v;
  }
}

// ================= kA: input attention + drop mask + X-frag writer ==========
__global__ __launch_bounds__(256)
void kA(const int* __restrict__ flag,
        const float* __restrict__ inp, const float* __restrict__ hx,
        const float* __restrict__ Wq_i, const float* __restrict__ Wk_i,
        const float* __restrict__ Wv_i, const float* __restrict__ W_read,
        half_t* __restrict__ xh, half_t* __restrict__ xl,
        float* __restrict__ hread, float* __restrict__ mask8,
        float* __restrict__ out_mask, float* __restrict__ out_bm)
{
  if (*flag != 0) return;
  const int t = threadIdx.x;
  const int n0 = blockIdx.x * 16, gbase = n0 * 128;
  __shared__ __align__(16) float inps[2048], hxs[2048], vsb[2048];
  __shared__ float qsb[1088], kslb[1088];
  __shared__ float Xf[2112];
  __shared__ float attb[160];
  __shared__ float m8_[16];

  for (int idx = t; idx < 512; idx += 256) {
    *reinterpret_cast<float4*>(&hxs[idx * 4]) =
        *reinterpret_cast<const float4*>(hx + gbase + idx * 4);
    *reinterpret_cast<float4*>(&inps[idx * 4]) =
        *reinterpret_cast<const float4*>(inp + gbase + idx * 4);
  }
  __syncthreads();
  for (int idx = t; idx < 1024; idx += 256) {
    int k16 = idx >> 6, d = idx & 63;
    float aq = 0.f, ak = 0.f;
#pragma unroll 8
    for (int i = 0; i < 128; i++) {
      aq += hxs[k16 * 128 + i]  * Wq_i[i * 64 + d];
      ak += inps[k16 * 128 + i] * Wk_i[i * 64 + d];
    }
    qsb[k16 * 68 + d] = aq; kslb[k16 * 68 + d] = ak;
  }
  for (int idx = t; idx < 2048; idx += 256) {
    int n16 = idx >> 7, j = idx & 127;
    float a = 0.f;
#pragma unroll 8
    for (int i = 0; i < 128; i++) a += inps[n16 * 128 + i] * Wv_i[i * 128 + j];
    vsb[idx] = a;
  }
  {
    int n16 = t >> 4, d = t & 15;
    float a = 0.f;
#pragma unroll 8
    for (int i = 0; i < 128; i++) a += hxs[n16 * 128 + i] * W_read[i * 16 + d];
    hread[(size_t)(n0 + n16) * 16 + d] = a;
  }
  __syncthreads();
  if (t < 128) {
    int b2 = t >> 6, k = (t >> 3) & 7, n = t & 7;
    float sc = 0.f;
#pragma unroll
    for (int d = 0; d < 64; d++)
      sc += qsb[(b2 * 8 + k) * 68 + d] * kslb[(b2 * 8 + n) * 68 + d];
    attb[b2 * 72 + k * 9 + n] = sc * 0.125f;
  } else if (t < 144) {
    int u = t - 128, b2 = u >> 3, k = u & 7;
    attb[b2 * 72 + k * 9 + 8] = 0.f;
  }
  __syncthreads();
  if (t < 16) {
    int b2 = t >> 3, k = t & 7;
    float* row = &attb[b2 * 72 + k * 9];
    float mx = row[0];
    for (int n = 1; n < 9; n++) mx = fmaxf(mx, row[n]);
    float e[9], ssum = 0.f;
    for (int n = 0; n < 9; n++) { e[n] = expf(row[n] - mx); ssum += e[n]; }
    for (int n = 0; n < 9; n++) row[n] = e[n] / ssum;
  }
  __syncthreads();
  if (t < 2) {
    bool taken[8] = {};
    for (int dd = 0; dd < 3; dd++) {
      int bi = 0; float bv = -1e30f;
      for (int k = 0; k < 8; k++) {
        float v = attb[t * 72 + k * 9 + 0];
        if (!taken[k] && v > bv) { bv = v; bi = k; }
      }
      taken[bi] = true;
    }
    for (int k = 0; k < 8; k++) m8_[t * 8 + k] = taken[k] ? 0.f : 1.f;
  }
  __syncthreads();
  for (int idx = t; idx < 2048; idx += 256) {
    int n16 = idx >> 7, j = idx & 127, b2 = n16 >> 3, k = n16 & 7;
    float a = 0.f;
#pragma unroll
    for (int n = 0; n < 8; n++) a += attb[b2 * 72 + k * 9 + n] * vsb[(b2 * 8 + n) * 128 + j];
    Xf[n16 * 132 + j] = a;
    out_mask[gbase + idx] = m8_[n16];
  }
  if (t < 16) { out_bm[n0 + t] = m8_[t]; mask8[n0 + t] = m8_[t]; }
  __syncthreads();
  // X-frag writer: unit = (ks, lane), value X[row=c15][k=ks*32+qd*8+j]
  for (int u = t; u < 512; u += 256) {
    int ks = u >> 6, lane = u & 63, c15 = lane & 15, qd = lane >> 4;
    int kb = ks * 32 + qd * 8;
    half8 hi, lo;
#pragma unroll
    for (int j = 0; j < 8; j++) {
      int k = kb + j;
      float v = (k < 128) ? Xf[c15 * 132 + k] : hxs[c15 * 128 + (k - 128)];
      half_t h = (half_t)v;
      hi[j] = h; lo[j] = (half_t)(v - (float)h);
    }
    size_t off = ((size_t)(blockIdx.x * 8 + ks) * 64 + lane) * 8;
    *reinterpret_cast<half8*>(xh + off) = hi;
    *reinterpret_cast<half8*>(xl + off) = lo;
  }
}

// ================= kB: gates GEMM + LSTM + selection =================
// 512 threads, 32 rows/block. Wave w: template m=w>>1, s-half sh=w&1.
__global__ __launch_bounds__(512, 2)
void kB(const int* __restrict__ flag, const half_t* __restrict__ wsp,
        const float* __restrict__ cx,
        const float* __restrict__ b_ih, const float* __restrict__ b_hh,
        const float* __restrict__ hread, const float* __restrict__ mask8,
        half_t* __restrict__ hbout, float* __restrict__ out_cx,
        float* __restrict__ out_ta)
{
  if (*flag != 0) return;
  const int t = threadIdx.x, lane = t & 63, w = t >> 6;
  const int m = w >> 1, sh = w & 1;
  const int c15 = lane & 15, qd = lane >> 4;
  const int n0 = blockIdx.x * 32;

  __shared__ __align__(16) half_t hth[32 * 520];
  __shared__ __align__(16) half_t htl[32 * 520];
  __shared__ float wks[2048];
  __shared__ float zb[128];
  __shared__ float m8s[32];
  __shared__ int msh[32];

  if (t < 32) m8s[t] = mask8[n0 + t];

  float4v acc[16][2];
#pragma unroll
  for (int ct = 0; ct < 16; ct++)
#pragma unroll
    for (int mt = 0; mt < 2; mt++) acc[ct][mt] = (float4v){0.f, 0.f, 0.f, 0.f};

  const half_t* xh = wsp + F_XH;
  const half_t* xl = wsp + F_XL;
  for (int ks = 0; ks < 8; ks++) {
    half8 ah[2], al[2];
#pragma unroll
    for (int mt = 0; mt < 2; mt++) {
      size_t aoff = ((size_t)((blockIdx.x * 2 + mt) * 8 + ks) * 64 + lane) * 8;
      ah[mt] = *reinterpret_cast<const half8*>(xh + aoff);
      al[mt] = *reinterpret_cast<const half8*>(xl + aoff);
    }
#pragma unroll
    for (int ct = 0; ct < 16; ct++) {
      int nt = (ct >> 2) * 8 + sh * 4 + (ct & 3);
      size_t boff = ((size_t)((m * 32 + nt) * 8 + ks) * 64 + lane) * 8;
      half8 bh = *reinterpret_cast<const half8*>(wsp + F_GH + boff);
      half8 bl = *reinterpret_cast<const half8*>(wsp + F_GL + boff);
#pragma unroll
      for (int mt = 0; mt < 2; mt++) {
        acc[ct][mt] = MFMA16(ah[mt], bh, acc[ct][mt]);
        acc[ct][mt] = MFMA16(ah[mt], bl, acc[ct][mt]);
        acc[ct][mt] = MFMA16(al[mt], bh, acc[ct][mt]);
      }
    }
  }
  // ---- LSTM epilogue: each thread owns (m; 4 s; 8 rows) ----
  float ccr[4][2][4];
#pragma unroll
  for (int c4 = 0; c4 < 4; c4++) {
    int s = sh * 64 + c4 * 16 + c15;
    float bi = b_ih[m * 512 + s]       + b_hh[m * 512 + s];
    float bf = b_ih[m * 512 + 128 + s] + b_hh[m * 512 + 128 + s];
    float bg = b_ih[m * 512 + 256 + s] + b_hh[m * 512 + 256 + s];
    float bo = b_ih[m * 512 + 384 + s] + b_hh[m * 512 + 384 + s];
#pragma unroll
    for (int mt = 0; mt < 2; mt++) {
#pragma unroll
      for (int rg = 0; rg < 4; rg++) {
        int row = mt * 16 + qd * 4 + rg;
        float iv = acc[c4][mt][rg]      + bi;
        float fv = acc[4 + c4][mt][rg]  + bf;
        float gv = acc[8 + c4][mt][rg]  + bg;
        float ov = acc[12 + c4][mt][rg] + bo;
        float cxv = cx[(size_t)(n0 + row) * 128 + s];
        float cc = sigm(fv) * cxv + sigm(iv) * tanhf(gv);
        float hh = sigm(ov) * tanhf(cc);
        ccr[c4][mt][rg] = cc;
        half_t hhi = (half_t)hh;
        hth[row * 520 + m * 128 + s] = hhi;
        htl[row * 520 + m * 128 + s] = (half_t)(hh - (float)hhi);
      }
    }
  }
  __syncthreads();
  // ---- write-key MFMA: wave w handles (m, row-tile sh) ----
  {
    float4v wa = (float4v){0.f, 0.f, 0.f, 0.f};
    const half_t* Wh = wsp + F_WWH + (m * 16 + c15) * 128 + qd * 8;
    const half_t* Wl = wsp + F_WWL + (m * 16 + c15) * 128 + qd * 8;
    const half_t* Hh = &hth[(sh * 16 + c15) * 520 + m * 128 + qd * 8];
    const half_t* Hl = &htl[(sh * 16 + c15) * 520 + m * 128 + qd * 8];
#pragma unroll
    for (int ks = 0; ks < 4; ks++) {
      half8 ahf = *reinterpret_cast<const half8*>(Hh + ks * 32);
      half8 alf = *reinterpret_cast<const half8*>(Hl + ks * 32);
      half8 bhf = *reinterpret_cast<const half8*>(Wh + ks * 32);
      half8 blf = *reinterpret_cast<const half8*>(Wl + ks * 32);
      wa = MFMA16(ahf, bhf, wa);
      wa = MFMA16(ahf, blf, wa);
      wa = MFMA16(alf, bhf, wa);
    }
#pragma unroll
    for (int rg = 0; rg < 4; rg++)
      wks[m * 512 + (sh * 16 + qd * 4 + rg) * 16 + c15] = wa[rg];
  }
  __syncthreads();
  if (t < 128) {
    int row = t >> 2, mm = t & 3;
    float lg = 0.f;
#pragma unroll
    for (int d = 0; d < 16; d++)
      lg += hread[(size_t)(n0 + row) * 16 + d] * wks[mm * 512 + row * 16 + d];
    zb[t] = lg + gumbel_at((unsigned)((n0 + row) * 4 + mm));
  }
  __syncthreads();
  if (t < 32) {
    int ms = 0; float best = zb[t * 4];
#pragma unroll
    for (int mm = 1; mm < 4; mm++)
      if (zb[t * 4 + mm] > best) { best = zb[t * 4 + mm]; ms = mm; }
    msh[t] = ms;
#pragma unroll
    for (int mm = 0; mm < 4; mm++)
      out_ta[(size_t)(n0 + t) * 4 + mm] = (mm == ms) ? 1.0f : 0.0f;
  }
  __syncthreads();
  // ---- cx out (owning wave m == msh[row]) ----
#pragma unroll
  for (int c4 = 0; c4 < 4; c4++) {
    int s = sh * 64 + c4 * 16 + c15;
#pragma unroll
    for (int mt = 0; mt < 2; mt++) {
#pragma unroll
      for (int rg = 0; rg < 4; rg++) {
        int row = mt * 16 + qd * 4 + rg;
        if (msh[row] == m) {
          float co = (m8s[row] != 0.f) ? ccr[c4][mt][rg]
                                       : cx[(size_t)(n0 + row) * 128 + s];
          out_cx[(size_t)(n0 + row) * 128 + s] = co;
        }
      }
    }
  }
  // ---- hb out (plain f16 [row][s]) ----
  for (int idx = t; idx < 4096; idx += 512) {
    int r = idx >> 7, s = idx & 127;
    hbout[(size_t)(n0 + r) * 128 + s] = hth[r * 520 + msh[r] * 128 + s];
  }
}

// ================= kC: communication attention + final hx blend =============
__global__ __launch_bounds__(256)
void kC(const int* __restrict__ flag, const half_t* __restrict__ wsp,
        const half_t* __restrict__ hbin, const float* __restrict__ mask8,
        const float* __restrict__ hx,
        const float* __restrict__ bf_c, const float* __restrict__ bg_c,
        float* __restrict__ out_hx)
{
  if (*flag != 0) return;
  const int t = threadIdx.x;
  const int n0 = blockIdx.x * 16;
  const int lane = t & 63, wv = t >> 6;
  const int col15 = lane & 15, quad = lane >> 4;

  __shared__ __align__(16) half_t hbF[2176], qcF[2176], kcF[2176], vcF[2176], oF[2176];
  __shared__ float attb[512];
  __shared__ float m8s[16];

  {
    int r = t >> 4, c8 = t & 15;
    *reinterpret_cast<half8*>(&hbF[r * 136 + c8 * 8]) =
        *reinterpret_cast<const half8*>(hbin + (size_t)(n0 + r) * 128 + c8 * 8);
  }
  if (t < 16) m8s[t] = mask8[n0 + t];
  __syncthreads();

  if (wv < 3) {
    float4v pacc[8];
#pragma unroll
    for (int ct = 0; ct < 8; ct++) pacc[ct] = (float4v){0.f, 0.f, 0.f, 0.f};
    const half_t* Bp = wsp + F_CQ + wv * 16384 + col15 * 128 + quad * 8;
    const half_t* Ap = &hbF[col15 * 136 + quad * 8];
#pragma unroll
    for (int ks = 0; ks < 4; ks++) {
      half8 a = *reinterpret_cast<const half8*>(Ap + ks * 32);
#pragma unroll
      for (int ct = 0; ct < 8; ct++) {
        half8 b = *reinterpret_cast<const half8*>(Bp + ct * 2048 + ks * 32);
        pacc[ct] = MFMA16(a, b, pacc[ct]);
      }
    }
    half_t* dst = (wv == 0) ? qcF : (wv == 1) ? kcF : vcF;
#pragma unroll
    for (int ct = 0; ct < 8; ct++)
#pragma unroll
      for (int rg = 0; rg < 4; rg++)
        dst[(quad * 4 + rg) * 136 + ct * 16 + col15] = (half_t)pacc[ct][rg];
  }
  __syncthreads();

  if (t < 64) {
    int b2 = t >> 5, h = (t >> 3) & 3, q = t & 7;
    float sc[8];
#pragma unroll
    for (int kq = 0; kq < 8; kq++) {
      float a = 0.f;
#pragma unroll
      for (int d = 0; d < 32; d++)
        a += (float)qcF[(b2 * 8 + q) * 136 + h * 32 + d] *
             (float)kcF[(b2 * 8 + kq) * 136 + h * 32 + d];
      sc[kq] = a * 0.17677669529663688110f;
    }
    float mx = sc[0];
#pragma unroll
    for (int kq = 1; kq < 8; kq++) mx = fmaxf(mx, sc[kq]);
    float e[8], ssum = 0.f;
#pragma unroll
    for (int kq = 0; kq < 8; kq++) { e[kq] = expf(sc[kq] - mx); ssum += e[kq]; }
#pragma unroll
    for (int kq = 0; kq < 8; kq++)
      attb[((b2 * 4 + h) * 8 + q) * 8 + kq] = e[kq] / ssum;
  }
  __syncthreads();

  for (int idx = t; idx < 2048; idx += 256) {
    int r = idx >> 7, cn = idx & 127, b2 = r >> 3, q = r & 7, h = cn >> 5;
    float a = 0.f;
#pragma unroll
    for (int kq = 0; kq < 8; kq++)
      a += attb[((b2 * 4 + h) * 8 + q) * 8 + kq] * (float)vcF[(b2 * 8 + kq) * 136 + cn];
    oF[r * 136 + cn] = (half_t)a;
  }
  __syncthreads();

  {
    float4v fa[2], ga[2];
#pragma unroll
    for (int tt = 0; tt < 2; tt++) {
      fa[tt] = (float4v){0.f, 0.f, 0.f, 0.f};
      ga[tt] = (float4v){0.f, 0.f, 0.f, 0.f};
    }
    const half_t* Ao = &oF[col15 * 136 + quad * 8];
    const half_t* Bf = wsp + F_CQ + 3 * 16384 + (wv * 32 + col15) * 128 + quad * 8;
    const half_t* Bg = wsp + F_CQ + 4 * 16384 + (wv * 32 + col15) * 128 + quad * 8;
#pragma unroll
    for (int ks = 0; ks < 4; ks++) {
      half8 a = *reinterpret_cast<const half8*>(Ao + ks * 32);
#pragma unroll
      for (int tt = 0; tt < 2; tt++) {
        half8 bfv = *reinterpret_cast<const half8*>(Bf + tt * 2048 + ks * 32);
        half8 bgv = *reinterpret_cast<const half8*>(Bg + tt * 2048 + ks * 32);
        fa[tt] = MFMA16(a, bfv, fa[tt]);
        ga[tt] = MFMA16(a, bgv, ga[tt]);
      }
    }
#pragma unroll
    for (int tt = 0; tt < 2; tt++) {
      int col = wv * 32 + tt * 16 + col15;
      float bfb = bf_c[col], bgb = bg_c[col];
#pragma unroll
      for (int rg = 0; rg < 4; rg++) {
        int row = quad * 4 + rg;
        float af = fa[tt][rg] + bfb;
        float ag = ga[tt][rg] + bgb;
        float comm = sigm(ag) * tanhf(af);
        float hbv = (float)hbF[row * 136 + col];
        float hv = (m8s[row] != 0.f) ? (hbv + comm)
                                     : hx[(size_t)(n0 + row) * 128 + col];
        out_hx[(size_t)(n0 + row) * 128 + col] = hv;
      }
    }
  }
}

// ================= tier-2 (round-5) kernels, kept as fallback =================
__global__ __launch_bounds__(256)
void k_wsplit(const float* __restrict__ W_ih, const float* __restrict__ W_hh,
              const float* __restrict__ W_write,
              const float* __restrict__ Wq_c, const float* __restrict__ Wk_c,
              const float* __restrict__ Wv_c, const float* __restrict__ Wf_c,
              const float* __restrict__ Wg_c, half_t* __restrict__ ws) {
  int i = blockIdx.x * 256 + threadIdx.x;
  if (i < 524288) {
    int n = i >> 8, k = i & 255;
    int m = n >> 9, g = n & 511;
    float w = (k < 128) ? W_ih[(m * 512 + g) * 128 + k]
                        : W_hh[(m * 512 + g) * 128 + (k - 128)];
    half_t h = (half_t)w;
    ws[GH + i] = h;
    ws[GL + i] = (half_t)(w - (float)h);
  } else if (i < 532480) {
    int j = i - 524288; int md = j >> 7, s = j & 127; int m = md >> 4, d = md & 15;
    float w = W_write[(m * 128 + s) * 16 + d];
    half_t h = (half_t)w;
    ws[WWH + j] = h;
    ws[WWL + j] = (half_t)(w - (float)h);
  } else if (i < 614400) {
    int j = i - 532480; int which = j >> 14, r = j & 16383;
    int col = r >> 7, k = r & 127;
    const float* Wsel = which == 0 ? Wq_c : which == 1 ? Wk_c :
                        which == 2 ? Wv_c : which == 3 ? Wf_c : Wg_c;
    ws[CQ + which * 16384 + r] = (half_t)Wsel[k * 128 + col];
  }
}

__global__ __launch_bounds__(256)
void k_scoff_mfma(const int* __restrict__ flag, const half_t* __restrict__ wsp,
                  const float* __restrict__ inp, const float* __restrict__ hx,
                  const float* __restrict__ cx,
                  const float* __restrict__ Wq_i, const float* __restrict__ Wk_i,
                  const float* __restrict__ Wv_i,
                  const float* __restrict__ bf_c, const float* __restrict__ bg_c,
                  const float* __restrict__ b_ih, const float* __restrict__ b_hh,
                  const float* __restrict__ W_read,
                  float* __restrict__ out_hx, float* __restrict__ out_cx,
                  float* __restrict__ out_mask, float* __restrict__ out_bm,
                  float* __restrict__ out_ta)
{
  if (*flag != 0) return;

  const int t = threadIdx.x;
  const int n0 = blockIdx.x * 16, gbase = n0 * 128;
  const int lane = t & 63, wv = t >> 6;
  const int col15 = lane & 15, quad = lane >> 4;

  __shared__ __align__(16) float hxs[2048];
  __shared__ __align__(16) float cxs[2048];
  __shared__ __align__(16) float vsb[2048];
  __shared__ float qsb[1088], kslb[1088];
  __shared__ __align__(16) half_t sXh[16 * 264];
  __shared__ __align__(16) half_t sXl[16 * 264];
  __shared__ __align__(16) half_t hth[16 * 520];
  __shared__ __align__(16) half_t htl[16 * 520];
  __shared__ __align__(16) half_t cts[16 * 512];
  __shared__ float wks[1024];
  __shared__ __align__(16) half_t hbF[16 * 136];
  __shared__ __align__(16) half_t oF[16 * 136];
  __shared__ __align__(16) half_t qcF[16 * 136];
  __shared__ __align__(16) half_t kcF[16 * 136];
  __shared__ __align__(16) half_t vcF[16 * 136];
  __shared__ float attb[512];
  __shared__ float hrs_[256];
  __shared__ float zbuf[64];
  __shared__ float m8_[16];
  __shared__ int   msh_[16];

  for (int idx = t; idx < 512; idx += 256) {
    *reinterpret_cast<float4*>(&hxs[idx * 4]) =
        *reinterpret_cast<const float4*>(hx + gbase + idx * 4);
    *reinterpret_cast<float4*>(&cxs[idx * 4]) =
        *reinterpret_cast<const float4*>(cx + gbase + idx * 4);
  }
  {
    __shared__ __align__(16) float inps[2048];
    for (int idx = t; idx < 512; idx += 256)
      *reinterpret_cast<float4*>(&inps[idx * 4]) =
          *reinterpret_cast<const float4*>(inp + gbase + idx * 4);
    __syncthreads();
    for (int idx = t; idx < 1024; idx += 256) {
      int k16 = idx >> 6, d = idx & 63;
      float aq = 0.f, ak = 0.f;
#pragma unroll 8
      for (int i = 0; i < 128; i++) {
        aq += hxs[k16 * 128 + i]  * Wq_i[i * 64 + d];
        ak += inps[k16 * 128 + i] * Wk_i[i * 64 + d];
      }
      qsb[k16 * 68 + d] = aq; kslb[k16 * 68 + d] = ak;
    }
    for (int idx = t; idx < 2048; idx += 256) {
      int n16 = idx >> 7, j = idx & 127;
      float a = 0.f;
#pragma unroll 8
      for (int i = 0; i < 128; i++) a += inps[n16 * 128 + i] * Wv_i[i * 128 + j];
      vsb[idx] = a;
    }
  }
  {
    int n16 = t >> 4, d = t & 15;
    float a = 0.f;
#pragma unroll 8
    for (int i = 0; i < 128; i++) a += hxs[n16 * 128 + i] * W_read[i * 16 + d];
    hrs_[t] = a;
  }
  for (int idx = t; idx < 2048; idx += 256) {
    int r = idx >> 7, i = idx & 127;
    float v = hxs[r * 128 + i];
    half_t hh = (half_t)v;
    sXh[r * 264 + 128 + i] = hh;
    sXl[r * 264 + 128 + i] = (half_t)(v - (float)hh);
  }
  __syncthreads();

  if (t < 128) {
    int b2 = t >> 6, k = (t >> 3) & 7, n = t & 7;
    float sc = 0.f;
#pragma unroll
    for (int d = 0; d < 64; d++)
      sc += qsb[(b2 * 8 + k) * 68 + d] * kslb[(b2 * 8 + n) * 68 + d];
    attb[b2 * 72 + k * 9 + n] = sc * 0.125f;
  } else if (t < 144) {
    int u = t - 128, b2 = u >> 3, k = u & 7;
    attb[b2 * 72 + k * 9 + 8] = 0.f;
  }
  __syncthreads();
  if (t < 16) {
    int b2 = t >> 3, k = t & 7;
    float* row = &attb[b2 * 72 + k * 9];
    float mx = row[0];
    for (int n = 1; n < 9; n++) mx = fmaxf(mx, row[n]);
    float e[9], ssum = 0.f;
    for (int n = 0; n < 9; n++) { e[n] = expf(row[n] - mx); ssum += e[n]; }
    for (int n = 0; n < 9; n++) row[n] = e[n] / ssum;
  }
  __syncthreads();
  if (t < 2) {
    bool taken[8] = {};
    for (int dd = 0; dd < 3; dd++) {
      int bi = 0; float bv = -1e30f;
      for (int k = 0; k < 8; k++) {
        float v = attb[t * 72 + k * 9 + 0];
        if (!taken[k] && v > bv) { bv = v; bi = k; }
      }
      taken[bi] = true;
    }
    for (int k = 0; k < 8; k++) m8_[t * 8 + k] = taken[k] ? 0.f : 1.f;
  }
  __syncthreads();
  for (int idx = t; idx < 2048; idx += 256) {
    int n16 = idx >> 7, j = idx & 127, b2 = n16 >> 3, k = n16 & 7;
    float a = 0.f;
#pragma unroll
    for (int n = 0; n < 8; n++) a += attb[b2 * 72 + k * 9 + n] * vsb[(b2 * 8 + n) * 128 + j];
    half_t hh = (half_t)a;
    sXh[n16 * 264 + j] = hh;
    sXl[n16 * 264 + j] = (half_t)(a - (float)hh);
    out_mask[gbase + idx] = m8_[n16];
  }
  if (t < 16) out_bm[n0 + t] = m8_[t];
  __syncthreads();
  for (int idx = t; idx < 2048; idx += 256) vsb[idx] = b_ih[idx] + b_hh[idx];
  __syncthreads();

  {
    float4v acc[32];
#pragma unroll
    for (int ct = 0; ct < 32; ct++) acc[ct] = (float4v){0.f, 0.f, 0.f, 0.f};
    const half_t* Ah = &sXh[col15 * 264 + quad * 8];
    const half_t* Al = &sXl[col15 * 264 + quad * 8];
    const half_t* Bh = wsp + GH + (size_t)(wv * 512 + col15) * 256 + quad * 8;
    const half_t* Bl = wsp + GL + (size_t)(wv * 512 + col15) * 256 + quad * 8;
    for (int ks = 0; ks < 8; ks++) {
      half8 ah = *reinterpret_cast<const half8*>(Ah + ks * 32);
      half8 al = *reinterpret_cast<const half8*>(Al + ks * 32);
#pragma unroll
      for (int ct = 0; ct < 32; ct++) {
        half8 bh = *reinterpret_cast<const half8*>(Bh + ct * 4096 + ks * 32);
        half8 bl = *reinterpret_cast<const half8*>(Bl + ct * 4096 + ks * 32);
        acc[ct] = MFMA16(ah, bh, acc[ct]);
        acc[ct] = MFMA16(ah, bl, acc[ct]);
        acc[ct] = MFMA16(al, bh, acc[ct]);
      }
    }
#pragma unroll
    for (int sh = 0; sh < 8; sh++) {
      int s = sh * 16 + col15;
      float bi = vsb[wv * 512 + s];
      float bf = vsb[wv * 512 + 128 + s];
      float bg = vsb[wv * 512 + 256 + s];
      float bo = vsb[wv * 512 + 384 + s];
#pragma unroll
      for (int rg = 0; rg < 4; rg++) {
        int row = quad * 4 + rg;
        float iv = acc[sh][rg] + bi;
        float fv = acc[8 + sh][rg] + bf;
        float gv = acc[16 + sh][rg] + bg;
        float ov = acc[24 + sh][rg] + bo;
        float cc = sigm(fv) * cxs[row * 128 + s] + sigm(iv) * tanhf(gv);
        float hh = sigm(ov) * tanhf(cc);
        half_t hhi = (half_t)hh;
        hth[row * 520 + wv * 128 + s] = hhi;
        htl[row * 520 + wv * 128 + s] = (half_t)(hh - (float)hhi);
        cts[row * 512 + wv * 128 + s] = (half_t)cc;
      }
    }
  }
  __syncthreads();

  {
    float4v wacc = (float4v){0.f, 0.f, 0.f, 0.f};
    const half_t* Wh = wsp + WWH + (wv * 16 + col15) * 128 + quad * 8;
    const half_t* Wl = wsp + WWL + (wv * 16 + col15) * 128 + quad * 8;
    const half_t* Hh = &hth[col15 * 520 + wv * 128 + quad * 8];
    const half_t* Hl = &htl[col15 * 520 + wv * 128 + quad * 8];
#pragma unroll
    for (int ks = 0; ks < 4; ks++) {
      half8 ah = *reinterpret_cast<const half8*>(Hh + ks * 32);
      half8 al = *reinterpret_cast<const half8*>(Hl + ks * 32);
      half8 bh = *reinterpret_cast<const half8*>(Wh + ks * 32);
      half8 bl = *reinterpret_cast<const half8*>(Wl + ks * 32);
      wacc = MFMA16(ah, bh, wacc);
      wacc = MFMA16(ah, bl, wacc);
      wacc = MFMA16(al, bh, wacc);
    }
#pragma unroll
    for (int rg = 0; rg < 4; rg++)
      wks[wv * 256 + (quad * 4 + rg) * 16 + col15] = wacc[rg];
  }
  __syncthreads();
  if (t < 64) {
    int row = t >> 2, mm = t & 3;
    float lg = 0.f;
#pragma unroll
    for (int d = 0; d < 16; d++) lg += hrs_[row * 16 + d] * wks[mm * 256 + row * 16 + d];
    zbuf[t] = lg + gumbel_at((unsigned)((n0 + row) * 4 + mm));
  }
  __syncthreads();
  if (t < 16) {
    int ms = 0; float best = zbuf[t * 4];
#pragma unroll
    for (int m = 1; m < 4; m++)
      if (zbuf[t * 4 + m] > best) { best = zbuf[t * 4 + m]; ms = m; }
    msh_[t] = ms;
#pragma unroll
    for (int m = 0; m < 4; m++) out_ta[(n0 + t) * 4 + m] = (m == ms) ? 1.0f : 0.0f;
  }
  __syncthreads();
  for (int idx = t; idx < 2048; idx += 256) {
    int r = idx >> 7, s = idx & 127;
    float cv = (float)cts[r * 512 + msh_[r] * 128 + s];
    out_cx[gbase + idx] = (m8_[r] != 0.f) ? cv : cxs[idx];
    hbF[r * 136 + s] = hth[r * 520 + msh_[r] * 128 + s];
  }
  __syncthreads();

  if (wv < 3) {
    float4v pacc[8];
#pragma unroll
    for (int ct = 0; ct < 8; ct++) pacc[ct] = (float4v){0.f, 0.f, 0.f, 0.f};
    const half_t* Bp = wsp + CQ + wv * 16384 + col15 * 128 + quad * 8;
    const half_t* Ap = &hbF[col15 * 136 + quad * 8];
#pragma unroll
    for (int ks = 0; ks < 4; ks++) {
      half8 a = *reinterpret_cast<const half8*>(Ap + ks * 32);
#pragma unroll
      for (int ct = 0; ct < 8; ct++) {
        half8 b = *reinterpret_cast<const half8*>(Bp + ct * 2048 + ks * 32);
        pacc[ct] = MFMA16(a, b, pacc[ct]);
      }
    }
    half_t* dst = (wv == 0) ? qcF : (wv == 1) ? kcF : vcF;
#pragma unroll
    for (int ct = 0; ct < 8; ct++)
#pragma unroll
      for (int rg = 0; rg < 4; rg++)
        dst[(quad * 4 + rg) * 136 + ct * 16 + col15] = (half_t)pacc[ct][rg];
  }
  __syncthreads();

  if (t < 64) {
    int b2 = t >> 5, h = (t >> 3) & 3, q = t & 7;
    float sc[8];
#pragma unroll
    for (int kq = 0; kq < 8; kq++) {
      float a = 0.f;
#pragma unroll
      for (int d = 0; d < 32; d++)
        a += (float)qcF[(b2 * 8 + q) * 136 + h * 32 + d] *
             (float)kcF[(b2 * 8 + kq) * 136 + h * 32 + d];
      sc[kq] = a * 0.17677669529663688110f;
    }
    float mx = sc[0];
#pragma unroll
    for (int kq = 1; kq < 8; kq++) mx = fmaxf(mx, sc[kq]);
    float e[8], ssum = 0.f;
#pragma unroll
    for (int kq = 0; kq < 8; kq++) { e[kq] = expf(sc[kq] - mx); ssum += e[kq]; }
#pragma unroll
    for (int kq = 0; kq < 8; kq++)
      attb[((b2 * 4 + h) * 8 + q) * 8 + kq] = e[kq] / ssum;
  }
  __syncthreads();

  for (int idx = t; idx < 2048; idx += 256) {
    int r = idx >> 7, cn = idx & 127, b2 = r >> 3, q = r & 7, h = cn >> 5;
    float a = 0.f;
#pragma unroll
    for (int kq = 0; kq < 8; kq++)
      a += attb[((b2 * 4 + h) * 8 + q) * 8 + kq] * (float)vcF[(b2 * 8 + kq) * 136 + cn];
    oF[r * 136 + cn] = (half_t)a;
  }
  __syncthreads();

  {
    float4v fa[2], ga[2];
#pragma unroll
    for (int tt = 0; tt < 2; tt++) {
      fa[tt] = (float4v){0.f, 0.f, 0.f, 0.f};
      ga[tt] = (float4v){0.f, 0.f, 0.f, 0.f};
    }
    const half_t* Ao = &oF[col15 * 136 + quad * 8];
    const half_t* Bf = wsp + CF + (wv * 32 + col15) * 128 + quad * 8;
    const half_t* Bg = wsp + CG + (wv * 32 + col15) * 128 + quad * 8;
#pragma unroll
    for (int ks = 0; ks < 4; ks++) {
      half8 a = *reinterpret_cast<const half8*>(Ao + ks * 32);
#pragma unroll
      for (int tt = 0; tt < 2; tt++) {
        half8 bf = *reinterpret_cast<const half8*>(Bf + tt * 2048 + ks * 32);
        half8 bg = *reinterpret_cast<const half8*>(Bg + tt * 2048 + ks * 32);
        fa[tt] = MFMA16(a, bf, fa[tt]);
        ga[tt] = MFMA16(a, bg, ga[tt]);
      }
    }
#pragma unroll
    for (int tt = 0; tt < 2; tt++) {
      int col = wv * 32 + tt * 16 + col15;
      float bfv = bf_c[col], bgv = bg_c[col];
#pragma unroll
      for (int rg = 0; rg < 4; rg++) {
        int row = quad * 4 + rg;
        float af = fa[tt][rg] + bfv;
        float ag = ga[tt][rg] + bgv;
        float comm = sigm(ag) * tanhf(af);
        float hb = (float)hth[row * 520 + msh_[row] * 128 + col] +
                   (float)htl[row * 520 + msh_[row] * 128 + col];
        float hv = (m8_[row] != 0.f) ? (hb + comm)
                                     : hx[(size_t)(n0 + row) * 128 + col];
        out_hx[(size_t)(n0 + row) * 128 + col] = hv;
      }
    }
  }
}

// ================= tier-3: round-4 VALU kernels (f32 / bf16) =================
template<int MODE> struct IO;
template<> struct IO<0> {
  static __device__ __forceinline__ float ld(const void* p, int i) { return ((const float*)p)[i]; }
  static __device__ __forceinline__ void st(void* p, int i, float v) { ((float*)p)[i] = v; }
};
template<> struct IO<1> {
  static __device__ __forceinline__ float ld(const void* p, int i) {
    return __bfloat162float(((const bf16*)p)[i]);
  }
  static __device__ __forceinline__ void st(void* p, int i, float v) {
    ((bf16*)p)[i] = __float2bfloat16(v);
  }
};

template<int MODE>
__global__ __launch_bounds__(256, 2)
void k_scoff(const int* __restrict__ flag,
             const void* __restrict__ inp, const void* __restrict__ hx,
             const void* __restrict__ cx,
             const void* __restrict__ Wq_i, const void* __restrict__ Wk_i,
             const void* __restrict__ Wv_i,
             const void* __restrict__ Wq_c, const void* __restrict__ Wk_c,
             const void* __restrict__ Wv_c, const void* __restrict__ Wf_c,
             const void* __restrict__ bf_c, const void* __restrict__ Wg_c,
             const void* __restrict__ bg_c,
             const void* __restrict__ W_ih, const void* __restrict__ W_hh,
             const void* __restrict__ b_ih, const void* __restrict__ b_hh,
             const void* __restrict__ W_read, const void* __restrict__ W_write,
             void* __restrict__ out_hx, void* __restrict__ out_cx,
             void* __restrict__ out_mask, void* __restrict__ out_bm,
             void* __restrict__ out_ta)
{
  if (*flag != MODE) return;

  const int t  = threadIdx.x;
  const int n0 = blockIdx.x * 16;
  const int gbase = n0 * 128;

  __shared__ float inps_os[2048];
  __shared__ float As[4096];
  __shared__ float Bs[8320];
  __shared__ float attbuf[512];
  __shared__ float hrs[256];
  __shared__ float m8[16];
  __shared__ int   msh[16];

  float* const qs  = Bs;
  float* const ksl = Bs + 1024;
  float* const vs  = Bs + 2048;
  float* const hxs = Bs + 4096;

  if constexpr (MODE == 1) {
    const unsigned* hx32 = (const unsigned*)((const bf16*)hx + gbase);
    const unsigned* in32 = (const unsigned*)((const bf16*)inp + gbase);
    for (int idx = t; idx < 1024; idx += 256) {
      unsigned wh = hx32[idx], wi = in32[idx];
      hxs[2 * idx]         = __uint_as_float(wh << 16);
      hxs[2 * idx + 1]     = __uint_as_float(wh & 0xffff0000u);
      inps_os[2 * idx]     = __uint_as_float(wi << 16);
      inps_os[2 * idx + 1] = __uint_as_float(wi & 0xffff0000u);
    }
  } else {
    const float* hxf = (const float*)hx + gbase;
    const float* inf_ = (const float*)inp + gbase;
    for (int idx = t; idx < 512; idx += 256) {
      *reinterpret_cast<float4*>(&hxs[idx * 4]) =
          *reinterpret_cast<const float4*>(hxf + idx * 4);
      *reinterpret_cast<float4*>(&inps_os[idx * 4]) =
          *reinterpret_cast<const float4*>(inf_ + idx * 4);
    }
  }
  __syncthreads();

  for (int idx = t; idx < 1024; idx += 256) {
    int k16 = idx >> 6, d = idx & 63;
    float aq = 0.f, ak = 0.f;
#pragma unroll 8
    for (int i = 0; i < 128; i++) {
      aq += hxs[k16 * 128 + i]     * IO<MODE>::ld(Wq_i, i * 64 + d);
      ak += inps_os[k16 * 128 + i] * IO<MODE>::ld(Wk_i, i * 64 + d);
    }
    qs[idx] = aq; ksl[idx] = ak;
  }
  for (int idx = t; idx < 2048; idx += 256) {
    int n16 = idx >> 7, j = idx & 127;
    float a = 0.f;
#pragma unroll 8
    for (int i = 0; i < 128; i++) a += inps_os[n16 * 128 + i] * IO<MODE>::ld(Wv_i, i * 128 + j);
    vs[idx] = a;
  }
  for (int idx = t; idx < 2048; idx += 256) {
    int i = idx >> 4, r = idx & 15;
    As[(128 + i) * 16 + r] = hxs[r * 128 + i];
  }
  {
    int n16 = t >> 4, d = t & 15;
    float a = 0.f;
#pragma unroll 8
    for (int i = 0; i < 128; i++) a += hxs[n16 * 128 + i] * IO<MODE>::ld(W_read, i * 16 + d);
    hrs[t] = a;
  }
  __syncthreads();

  if (t < 128) {
    int b2 = t >> 6, k = (t >> 3) & 7, n = t & 7;
    float sc = 0.f;
#pragma unroll
    for (int d = 0; d < 64; d++) sc += qs[(b2 * 8 + k) * 64 + d] * ksl[(b2 * 8 + n) * 64 + d];
    attbuf[b2 * 72 + k * 9 + n] = sc * 0.125f;
  } else if (t < 144) {
    int u = t - 128, b2 = u >> 3, k = u & 7;
    attbuf[b2 * 72 + k * 9 + 8] = 0.f;
  }
  __syncthreads();
  if (t < 16) {
    int b2 = t >> 3, k = t & 7;
    float* row = &attbuf[b2 * 72 + k * 9];
    float mx = row[0];
    for (int n = 1; n < 9; n++) mx = fmaxf(mx, row[n]);
    float e[9], ssum = 0.f;
    for (int n = 0; n < 9; n++) { e[n] = expf(row[n] - mx); ssum += e[n]; }
    for (int n = 0; n < 9; n++) row[n] = e[n] / ssum;
  }
  __syncthreads();
  if (t < 2) {
    bool taken[8] = {};
    for (int dd = 0; dd < 3; dd++) {
      int bi = 0; float bv = -1e30f;
      for (int k = 0; k < 8; k++) {
        float v = attbuf[t * 72 + k * 9 + 0];
        if (!taken[k] && v > bv) { bv = v; bi = k; }
      }
      taken[bi] = true;
    }
    for (int k = 0; k < 8; k++) m8[t * 8 + k] = taken[k] ? 0.f : 1.f;
  }
  __syncthreads();
  for (int idx = t; idx < 2048; idx += 256) {
    int n16 = idx >> 7, j = idx & 127, b2 = n16 >> 3, k = n16 & 7;
    float a = 0.f;
#pragma unroll
    for (int n = 0; n < 8; n++) a += attbuf[b2 * 72 + k * 9 + n] * vs[(b2 * 8 + n) * 128 + j];
    As[j * 16 + n16] = a;
    IO<MODE>::st(out_mask, gbase + idx, m8[n16]);
  }
  if (t < 16) IO<MODE>::st(out_bm, n0 + t, m8[t]);
  __syncthreads();

  const int s = t & 127, rg = t >> 7;
  float cvals[8];
#pragma unroll
  for (int j = 0; j < 8; j++) cvals[j] = IO<MODE>::ld(cx, (n0 + rg * 8 + j) * 128 + s);

  float ht[8][4], ct[8][4];
  const int sq = t >> 1, hf = t & 1;

#pragma unroll
  for (int m = 0; m < 4; m++) {
    float acc[8][4];
#pragma unroll
    for (int j = 0; j < 8; j++)
#pragma unroll
      for (int q = 0; q < 4; q++) acc[j][q] = 0.f;

    for (int kc = 0; kc < 256; kc += 16) {
      __syncthreads();
      {
        const int kb = (kc & 127) + hf * 8;
        float e[4][8];
        if constexpr (MODE == 1) {
          const bf16* Wsrc = (const bf16*)((kc < 128) ? W_ih : W_hh);
          uint4 wq[4];
#pragma unroll
          for (int q = 0; q < 4; q++)
            wq[q] = *reinterpret_cast<const uint4*>(Wsrc + ((m * 512 + q * 128 + sq) << 7) + kb);
#pragma unroll
          for (int q = 0; q < 4; q++) {
            unsigned w0 = wq[q].x, w1 = wq[q].y, w2 = wq[q].z, w3 = wq[q].w;
            e[q][0] = __uint_as_float(w0 << 16); e[q][1] = __uint_as_float(w0 & 0xffff0000u);
            e[q][2] = __uint_as_float(w1 << 16); e[q][3] = __uint_as_float(w1 & 0xffff0000u);
            e[q][4] = __uint_as_float(w2 << 16); e[q][5] = __uint_as_float(w2 & 0xffff0000u);
            e[q][6] = __uint_as_float(w3 << 16); e[q][7] = __uint_as_float(w3 & 0xffff0000u);
          }
        } else {
          const float* Wsrc = (const float*)((kc < 128) ? W_ih : W_hh);
#pragma unroll
          for (int q = 0; q < 4; q++) {
            const float* rowp = Wsrc + ((m * 512 + q * 128 + sq) << 7) + kb;
            float4 lo = *reinterpret_cast<const float4*>(rowp);
            float4 hi = *reinterpret_cast<const float4*>(rowp + 4);
            e[q][0] = lo.x; e[q][1] = lo.y; e[q][2] = lo.z; e[q][3] = lo.w;
            e[q][4] = hi.x; e[q][5] = hi.y; e[q][6] = hi.z; e[q][7] = hi.w;
          }
        }
#pragma unroll
        for (int c = 0; c < 8; c++) {
          float4 v; v.x = e[0][c]; v.y = e[1][c]; v.z = e[2][c]; v.w = e[3][c];
          *reinterpret_cast<float4*>(&Bs[(hf * 8 + c) * 520 + sq * 4]) = v;
        }
      }
      __syncthreads();
#pragma unroll
      for (int kk = 0; kk < 16; kk++) {
        const float4* ap = reinterpret_cast<const float4*>(&As[(kc + kk) * 16 + rg * 8]);
        float4 a0 = ap[0], a1 = ap[1];
        float4 bb = *reinterpret_cast<const float4*>(&Bs[kk * 520 + s * 4]);
        float av[8] = {a0.x, a0.y, a0.z, a0.w, a1.x, a1.y, a1.z, a1.w};
#pragma unroll
        for (int j = 0; j < 8; j++) {
          acc[j][0] += av[j] * bb.x;
          acc[j][1] += av[j] * bb.y;
          acc[j][2] += av[j] * bb.z;
          acc[j][3] += av[j] * bb.w;
        }
      }
    }
    float badd[4];
#pragma unroll
    for (int q = 0; q < 4; q++)
      badd[q] = IO<MODE>::ld(b_ih, m * 512 + q * 128 + s) +
                IO<MODE>::ld(b_hh, m * 512 + q * 128 + s);
#pragma unroll
    for (int j = 0; j < 8; j++) {
      float ig = acc[j][0] + badd[0];
      float fg = acc[j][1] + badd[1];
      float gg = acc[j][2] + badd[2];
      float og = acc[j][3] + badd[3];
      float c_t = sigm(fg) * cvals[j] + sigm(ig) * tanhf(gg);
      float h_t = sigm(og) * tanhf(c_t);
      ct[j][m] = c_t; ht[j][m] = h_t;
    }
  }

  __syncthreads();
#pragma unroll
  for (int j = 0; j < 8; j++) {
    int r = rg * 8 + j;
#pragma unroll
    for (int m = 0; m < 4; m++) Bs[r * 520 + m * 128 + s] = ht[j][m];
  }
  __syncthreads();
  {
    const int row = t >> 4, d = t & 15;
    const float hr = hrs[t];
    float lg[4];
#pragma unroll
    for (int m = 0; m < 4; m++) {
      float wk = 0.f;
#pragma unroll 8
      for (int ss = 0; ss < 128; ss++)
        wk += Bs[row * 520 + m * 128 + ss] * IO<MODE>::ld(W_write, (m * 128 + ss) * 16 + d);
      float p = hr * wk;
      p += __shfl_xor(p, 1, 64);
      p += __shfl_xor(p, 2, 64);
      p += __shfl_xor(p, 4, 64);
      p += __shfl_xor(p, 8, 64);
      lg[m] = p;
    }
    if (d == 0) {
      const int n = n0 + row;
      float z[4];
#pragma unroll
      for (int m = 0; m < 4; m++) z[m] = lg[m] + gumbel_at((unsigned)(n * 4 + m));
      int ms = 0; float best = z[0];
#pragma unroll
      for (int m = 1; m < 4; m++) if (z[m] > best) { best = z[m]; ms = m; }
      msh[row] = ms;
#pragma unroll
      for (int m = 0; m < 4; m++)
        IO<MODE>::st(out_ta, n * 4 + m, (m == ms) ? 1.0f : 0.0f);
    }
  }
  __syncthreads();
#pragma unroll
  for (int j = 0; j < 8; j++) {
    int r = rg * 8 + j;
    int ms = msh[r];
    float cv = ct[j][0];
    if (ms == 1) cv = ct[j][1];
    else if (ms == 2) cv = ct[j][2];
    else if (ms == 3) cv = ct[j][3];
    float co = (m8[r] != 0.f) ? cv : cvals[j];
    IO<MODE>::st(out_cx, (n0 + r) * 128 + s, co);
  }

  __syncthreads();
  for (int idx = t; idx < 2048; idx += 256) {
    int r = idx >> 7, col = idx & 127;
    As[idx] = Bs[r * 520 + msh[r] * 128 + col];
  }
  __syncthreads();
  for (int idx = t; idx < 2048; idx += 256) {
    int r = idx >> 7, col = idx & 127;
    float aq = 0.f, ak = 0.f, av = 0.f;
#pragma unroll 8
    for (int i = 0; i < 128; i++) {
      float h = As[r * 128 + i];
      aq += h * IO<MODE>::ld(Wq_c, i * 128 + col);
      ak += h * IO<MODE>::ld(Wk_c, i * 128 + col);
      av += h * IO<MODE>::ld(Wv_c, i * 128 + col);
    }
    Bs[idx] = aq; Bs[2048 + idx] = ak; Bs[4096 + idx] = av;
  }
  __syncthreads();
  if (t < 64) {
    int b2 = t >> 5, h = (t >> 3) & 3, q = t & 7;
    float sc[8];
#pragma unroll
    for (int kq = 0; kq < 8; kq++) {
      float a = 0.f;
#pragma unroll
      for (int d = 0; d < 32; d++)
        a += Bs[(b2 * 8 + q) * 128 + h * 32 + d] * Bs[2048 + (b2 * 8 + kq) * 128 + h * 32 + d];
      sc[kq] = a * 0.17677669529663688110f;
    }
    float mx = sc[0];
#pragma unroll
    for (int kq = 1; kq < 8; kq++) mx = fmaxf(mx, sc[kq]);
    float e[8], ssum = 0.f;
#pragma unroll
    for (int kq = 0; kq < 8; kq++) { e[kq] = expf(sc[kq] - mx); ssum += e[kq]; }
#pragma unroll
    for (int kq = 0; kq < 8; kq++)
      attbuf[((b2 * 4 + h) * 8 + q) * 8 + kq] = e[kq] / ssum;
  }
  __syncthreads();
  for (int idx = t; idx < 2048; idx += 256) {
    int r = idx >> 7, col = idx & 127, b2 = r >> 3, q = r & 7, h = col >> 5;
    float a = 0.f;
#pragma unroll
    for (int kq = 0; kq < 8; kq++)
      a += attbuf[((b2 * 4 + h) * 8 + q) * 8 + kq] * Bs[4096 + (b2 * 8 + kq) * 128 + col];
    inps_os[idx] = a;
  }
  __syncthreads();
  for (int idx = t; idx < 2048; idx += 256) {
    int r = idx >> 7, col = idx & 127;
    float af = IO<MODE>::ld(bf_c, col);
    float ag = IO<MODE>::ld(bg_c, col);
#pragma unroll 8
    for (int d = 0; d < 128; d++) {
      float o = inps_os[r * 128 + d];
      af += o * IO<MODE>::ld(Wf_c, d * 128 + col);
      ag += o * IO<MODE>::ld(Wg_c, d * 128 + col);
    }
    float comm = sigm(ag) * tanhf(af);
    float hv = (m8[r] != 0.f) ? (As[r * 128 + col] + comm)
                              : IO<MODE>::ld(hx, gbase + idx);
    IO<MODE>::st(out_hx, gbase + idx, hv);
  }
}

// ============================ launch ============================
extern "C" void kernel_launch(void* const* d_in, const int* in_sizes, int n_in,
                              void* d_out, int out_size, void* d_ws, size_t ws_size,
                              hipStream_t stream) {
  const void* inp     = d_in[0];
  const void* hx      = d_in[1];
  const void* cx      = d_in[2];
  const void* Wq_i    = d_in[3];
  const void* Wk_i    = d_in[4];
  const void* Wv_i    = d_in[5];
  const void* Wq_c    = d_in[6];
  const void* Wk_c    = d_in[7];
  const void* Wv_c    = d_in[8];
  const void* Wf_c    = d_in[9];
  const void* bf_c    = d_in[10];
  const void* Wg_c    = d_in[11];
  const void* bg_c    = d_in[12];
  const void* W_ih    = d_in[13];
  const void* W_hh    = d_in[14];
  const void* b_ih    = d_in[15];
  const void* b_hh    = d_in[16];
  const void* W_read  = d_in[17];
  const void* W_write = d_in[18];

  auto off_f32 = [&](int e) -> float* { return (float*)d_out + e; };
  auto off_b16 = [&](int e) -> void* { return (void*)((bf16*)d_out + e); };

  if (ws_size >= WS2_NEED) {
    half_t* wsp = (half_t*)d_ws;
    float* gws = (float*)((char*)d_ws + 2 * F_END);
    float* hread = gws + G_HREAD;
    float* mask8 = gws + G_MASK8;
    int* flag = (int*)(gws + G_FLAG);
    k_detect<<<1, 256, 0, stream>>>(inp, flag);
    k_wsplit2<<<328, 256, 0, stream>>>(flag, (const float*)W_ih, (const float*)W_hh,
                                       (const float*)W_write,
                                       (const float*)Wq_c, (const float*)Wk_c,
                                       (const float*)Wv_c, (const float*)Wf_c,
                                       (const float*)Wg_c, wsp);
    kA<<<1024, 256, 0, stream>>>(flag, (const float*)inp, (const float*)hx,
                                 (const float*)Wq_i, (const float*)Wk_i,
                                 (const float*)Wv_i, (const float*)W_read,
                                 wsp + F_XH, wsp + F_XL, hread, mask8,
                                 off_f32(4194304), off_f32(6291456));
    kB<<<512, 512, 0, stream>>>(flag, wsp, (const float*)cx,
                                (const float*)b_ih, (const float*)b_hh,
                                hread, mask8, wsp + F_HB,
                                off_f32(2097152), off_f32(6307840));
    kC<<<1024, 256, 0, stream>>>(flag, wsp, wsp + F_HB, mask8, (const float*)hx,
                                 (const float*)bf_c, (const float*)bg_c, off_f32(0));
    k_scoff<1><<<1024, 256, 0, stream>>>(flag, inp, hx, cx, Wq_i, Wk_i, Wv_i,
                                         Wq_c, Wk_c, Wv_c, Wf_c, bf_c, Wg_c, bg_c,
                                         W_ih, W_hh, b_ih, b_hh, W_read, W_write,
                                         off_b16(0), off_b16(2097152), off_b16(4194304),
                                         off_b16(6291456), off_b16(6307840));
  } else if (ws_size >= WS_NEED) {
    half_t* wsp = (half_t*)d_ws;
    int* flag = (int*)((char*)d_ws + WS_FLAG_OFF);
    k_detect<<<1, 256, 0, stream>>>(inp, flag);
    k_wsplit<<<2400, 256, 0, stream>>>((const float*)W_ih, (const float*)W_hh,
                                       (const float*)W_write,
                                       (const float*)Wq_c, (const float*)Wk_c,
                                       (const float*)Wv_c, (const float*)Wf_c,
                                       (const float*)Wg_c, wsp);
    k_scoff_mfma<<<1024, 256, 0, stream>>>(flag, wsp,
        (const float*)inp, (const float*)hx, (const float*)cx,
        (const float*)Wq_i, (const float*)Wk_i, (const float*)Wv_i,
        (const float*)bf_c, (const float*)bg_c,
        (const float*)b_ih, (const float*)b_hh, (const float*)W_read,
        off_f32(0), off_f32(2097152), off_f32(4194304),
        off_f32(6291456), off_f32(6307840));
    k_scoff<1><<<1024, 256, 0, stream>>>(flag, inp, hx, cx, Wq_i, Wk_i, Wv_i,
                                         Wq_c, Wk_c, Wv_c, Wf_c, bf_c, Wg_c, bg_c,
                                         W_ih, W_hh, b_ih, b_hh, W_read, W_write,
                                         off_b16(0), off_b16(2097152), off_b16(4194304),
                                         off_b16(6291456), off_b16(6307840));
  } else {
    int* flag = (int*)d_ws;
    k_detect<<<1, 256, 0, stream>>>(inp, flag);
    k_scoff<0><<<1024, 256, 0, stream>>>(flag, inp, hx, cx, Wq_i, Wk_i, Wv_i,
                                         Wq_c, Wk_c, Wv_c, Wf_c, bf_c, Wg_c, bg_c,
                                         W_ih, W_hh, b_ih, b_hh, W_read, W_write,
                                         (void*)off_f32(0), (void*)off_f32(2097152),
                                         (void*)off_f32(4194304), (void*)off_f32(6291456),
                                         (void*)off_f32(6307840));
    k_scoff<1><<<1024, 256, 0, stream>>>(flag, inp, hx, cx, Wq_i, Wk_i, Wv_i,
                                         Wq_c, Wk_c, Wv_c, Wf_c, bf_c, Wg_c, bg_c,
                                         W_ih, W_hh, b_ih, b_hh, W_read, W_write,
                                         off_b16(0), off_b16(2097152), off_b16(4194304),
                                         off_b16(6291456), off_b16(6307840));
  }
}

// Round 7
// 308.000 us; speedup vs baseline: 2.2729x; 1.1925x over previous
//
#include <hip/hip_runtime.h>
#include <hip/hip_bf16.h>
#include <stdint.h>

typedef __hip_bfloat16 bf16;
typedef _Float16 half_t;
typedef __attribute__((ext_vector_type(8))) _Float16 half8;
typedef __attribute__((ext_vector_type(4))) float float4v;

// ---------------- threefry2x32 (exact JAX semantics) ----------------
struct TF2 { unsigned a, b; };
__host__ __device__ constexpr unsigned rotl32(unsigned v, int r) {
  return (v << r) | (v >> (32 - r));
}
__host__ __device__ constexpr TF2 tf2x32(unsigned k0, unsigned k1, unsigned x0, unsigned x1) {
  unsigned ks2 = k0 ^ k1 ^ 0x1BD11BDAu;
  x0 += k0; x1 += k1;
  const int ra[4] = {13, 15, 26, 6};
  const int rb[4] = {17, 29, 16, 24};
  for (int i = 0; i < 4; i++) { x0 += x1; x1 = rotl32(x1, ra[i]); x1 ^= x0; }
  x0 += k1; x1 += ks2 + 1u;
  for (int i = 0; i < 4; i++) { x0 += x1; x1 = rotl32(x1, rb[i]); x1 ^= x0; }
  x0 += ks2; x1 += k0 + 2u;
  for (int i = 0; i < 4; i++) { x0 += x1; x1 = rotl32(x1, ra[i]); x1 ^= x0; }
  x0 += k0; x1 += k1 + 3u;
  for (int i = 0; i < 4; i++) { x0 += x1; x1 = rotl32(x1, rb[i]); x1 ^= x0; }
  x0 += k1; x1 += ks2 + 4u;
  for (int i = 0; i < 4; i++) { x0 += x1; x1 = rotl32(x1, ra[i]); x1 ^= x0; }
  x0 += ks2; x1 += k0 + 5u;
  return TF2{x0, x1};
}
constexpr unsigned GK0 = tf2x32(0u, 0u, 0u, 12345u).a;
constexpr unsigned GK1 = tf2x32(0u, 0u, 0u, 12345u).b;

// JAX threefry_partitionable (default) 32-bit bits: counter (0, j), XOR-fold.
__device__ __forceinline__ float gumbel_at(unsigned j) {
  TF2 r = tf2x32(GK0, GK1, 0u, j);
  unsigned bits = r.a ^ r.b;
  float u = __uint_as_float((bits >> 9) | 0x3f800000u) - 1.0f;
  u = fmaxf(1.17549435e-38f, u + 1.17549435e-38f);
  return -logf(-logf(u));
}

__device__ __forceinline__ float sigm(float x) { return 1.0f / (1.0f + expf(-x)); }

#define MFMA16(a, b, c) __builtin_amdgcn_mfma_f32_16x16x32_f16((a), (b), (c), 0, 0, 0)

// ================= tier-2 (round-5 monolith) ws layout =================
constexpr int GH  = 0;
constexpr int GL  = 524288;
constexpr int WWH = 1048576;
constexpr int WWL = 1056768;
constexpr int CQ  = 1064960;
constexpr int CF  = 1114112;
constexpr int CG  = 1130496;
constexpr int WS_HALF_TOTAL = 1146880;
constexpr size_t WS_FLAG_OFF = (size_t)WS_HALF_TOTAL * 2;
constexpr size_t WS_NEED     = WS_FLAG_OFF + 64;

// ================= tier-1 (split path) ws layout, half element offsets =====
constexpr size_t F_GH  = 0;          // swizzled gates hi: [m][nt32][ks8][lane64][8]
constexpr size_t F_GL  = 524288;
constexpr size_t F_WWH = 1048576;    // W_write hi [m*16+d][s]
constexpr size_t F_WWL = 1056768;
constexpr size_t F_CQ  = 1064960;    // 5 × 16384 (q,k,v,f,g) [col][k]
constexpr size_t F_XH  = 1146880;    // X frag: [rt1024][ks8][lane64][8]
constexpr size_t F_XL  = 5341184;
constexpr size_t F_HB  = 9535488;    // hb plain [row][s] f16
constexpr size_t F_END = 11632640;   // halfs
constexpr size_t G_HREAD = 0;        // f32 idx in f32 region
constexpr size_t G_MASK8 = 262144;
constexpr size_t G_FLAG  = 278528;
constexpr size_t WS2_NEED = F_END * 2 + (G_FLAG + 16) * 4;

// ---------------- dtype probe: bf16-decode of f32 data explodes ----------------
__global__ void k_detect(const void* inp, int* flag) {
  __shared__ int bad;
  if (threadIdx.x == 0) bad = 0;
  __syncthreads();
  const unsigned short* u = (const unsigned short*)inp;
  for (int i = threadIdx.x; i < 1024; i += 256) {
    float v = __uint_as_float(((unsigned)u[i]) << 16);
    if (!(fabsf(v) < 64.f)) atomicOr(&bad, 1);
  }
  __syncthreads();
  if (threadIdx.x == 0) *flag = bad ? 0 : 1;   // 0 = f32, 1 = bf16
}

// ================= tier-1 weight split (frag-swizzled gates) =================
__global__ __launch_bounds__(256)
void k_wsplit2(const int* __restrict__ flag,
               const float* __restrict__ W_ih, const float* __restrict__ W_hh,
               const float* __restrict__ W_write,
               const float* __restrict__ Wq_c, const float* __restrict__ Wk_c,
               const float* __restrict__ Wv_c, const float* __restrict__ Wf_c,
               const float* __restrict__ Wg_c, half_t* __restrict__ ws) {
  if (*flag != 0) return;
  int tid = blockIdx.x * 256 + threadIdx.x;
  if (tid < 65536) {                 // gates B-frags: unit = (m,nt,ks,lane)
    int m = tid >> 14, nt = (tid >> 9) & 31, ks = (tid >> 6) & 7, lane = tid & 63;
    int n = m * 512 + nt * 16 + (lane & 15);
    int kb = ks * 32 + (lane >> 4) * 8;
    half8 hi, lo;
#pragma unroll
    for (int j = 0; j < 8; j++) {
      int k = kb + j;
      float w = (k < 128) ? W_ih[n * 128 + k] : W_hh[n * 128 + (k - 128)];
      half_t h = (half_t)w;
      hi[j] = h; lo[j] = (half_t)(w - (float)h);
    }
    *reinterpret_cast<half8*>(ws + F_GH + (size_t)tid * 8) = hi;
    *reinterpret_cast<half8*>(ws + F_GL + (size_t)tid * 8) = lo;
  } else if (tid < 73728) {          // W_write: [m*16+d][s]
    int j = tid - 65536; int md = j >> 7, s = j & 127; int m = md >> 4, d = md & 15;
    float w = W_write[(m * 128 + s) * 16 + d];
    half_t h = (half_t)w;
    ws[F_WWH + j] = h;
    ws[F_WWL + j] = (half_t)(w - (float)h);
  } else if (tid < 83968) {          // comm mats transposed [col][k], half8 units
    int u = tid - 73728;
    int which = u >> 11, r8 = u & 2047;
    int col = r8 >> 4, k8 = r8 & 15;
    const float* Wsel = which == 0 ? Wq_c : which == 1 ? Wk_c :
                        which == 2 ? Wv_c : which == 3 ? Wf_c : Wg_c;
    half8 v;
#pragma unroll
    for (int j = 0; j < 8; j++) v[j] = (half_t)Wsel[(k8 * 8 + j) * 128 + col];
    *reinterpret_cast<half8*>(ws + F_CQ + (size_t)which * 16384 + col * 128 + k8 * 8) = v;
  }
}

// ================= kA: input attention + drop mask + X-frag writer ==========
__global__ __launch_bounds__(256)
void kA(const int* __restrict__ flag,
        const float* __restrict__ inp, const float* __restrict__ hx,
        const float* __restrict__ Wq_i, const float* __restrict__ Wk_i,
        const float* __restrict__ Wv_i, const float* __restrict__ W_read,
        half_t* __restrict__ xh, half_t* __restrict__ xl,
        float* __restrict__ hread, float* __restrict__ mask8,
        float* __restrict__ out_mask, float* __restrict__ out_bm)
{
  if (*flag != 0) return;
  const int t = threadIdx.x;
  const int n0 = blockIdx.x * 16, gbase = n0 * 128;
  __shared__ __align__(16) float inps[2048], hxs[2048], vsb[2048];
  __shared__ float qsb[1088], kslb[1088];
  __shared__ float Xf[2112];
  __shared__ float attb[160];
  __shared__ float m8_[16];

  for (int idx = t; idx < 512; idx += 256) {
    *reinterpret_cast<float4*>(&hxs[idx * 4]) =
        *reinterpret_cast<const float4*>(hx + gbase + idx * 4);
    *reinterpret_cast<float4*>(&inps[idx * 4]) =
        *reinterpret_cast<const float4*>(inp + gbase + idx * 4);
  }
  __syncthreads();
  for (int idx = t; idx < 1024; idx += 256) {
    int k16 = idx >> 6, d = idx & 63;
    float aq0 = 0.f, aq1 = 0.f, aq2 = 0.f, aq3 = 0.f;
    float ak0 = 0.f, ak1 = 0.f, ak2 = 0.f, ak3 = 0.f;
#pragma unroll 8
    for (int i = 0; i < 128; i += 4) {
      aq0 += hxs[k16 * 128 + i]     * Wq_i[i * 64 + d];
      aq1 += hxs[k16 * 128 + i + 1] * Wq_i[(i + 1) * 64 + d];
      aq2 += hxs[k16 * 128 + i + 2] * Wq_i[(i + 2) * 64 + d];
      aq3 += hxs[k16 * 128 + i + 3] * Wq_i[(i + 3) * 64 + d];
      ak0 += inps[k16 * 128 + i]     * Wk_i[i * 64 + d];
      ak1 += inps[k16 * 128 + i + 1] * Wk_i[(i + 1) * 64 + d];
      ak2 += inps[k16 * 128 + i + 2] * Wk_i[(i + 2) * 64 + d];
      ak3 += inps[k16 * 128 + i + 3] * Wk_i[(i + 3) * 64 + d];
    }
    qsb[k16 * 68 + d]  = (aq0 + aq1) + (aq2 + aq3);
    kslb[k16 * 68 + d] = (ak0 + ak1) + (ak2 + ak3);
  }
  for (int idx = t; idx < 2048; idx += 256) {
    int n16 = idx >> 7, j = idx & 127;
    float a0 = 0.f, a1 = 0.f, a2 = 0.f, a3 = 0.f;
#pragma unroll 8
    for (int i = 0; i < 128; i += 4) {
      a0 += inps[n16 * 128 + i]     * Wv_i[i * 128 + j];
      a1 += inps[n16 * 128 + i + 1] * Wv_i[(i + 1) * 128 + j];
      a2 += inps[n16 * 128 + i + 2] * Wv_i[(i + 2) * 128 + j];
      a3 += inps[n16 * 128 + i + 3] * Wv_i[(i + 3) * 128 + j];
    }
    vsb[idx] = (a0 + a1) + (a2 + a3);
  }
  {
    int n16 = t >> 4, d = t & 15;
    float a0 = 0.f, a1 = 0.f, a2 = 0.f, a3 = 0.f;
#pragma unroll 8
    for (int i = 0; i < 128; i += 4) {
      a0 += hxs[n16 * 128 + i]     * W_read[i * 16 + d];
      a1 += hxs[n16 * 128 + i + 1] * W_read[(i + 1) * 16 + d];
      a2 += hxs[n16 * 128 + i + 2] * W_read[(i + 2) * 16 + d];
      a3 += hxs[n16 * 128 + i + 3] * W_read[(i + 3) * 16 + d];
    }
    hread[(size_t)(n0 + n16) * 16 + d] = (a0 + a1) + (a2 + a3);
  }
  __syncthreads();
  if (t < 128) {
    int b2 = t >> 6, k = (t >> 3) & 7, n = t & 7;
    float sc = 0.f;
#pragma unroll
    for (int d = 0; d < 64; d++)
      sc += qsb[(b2 * 8 + k) * 68 + d] * kslb[(b2 * 8 + n) * 68 + d];
    attb[b2 * 72 + k * 9 + n] = sc * 0.125f;
  } else if (t < 144) {
    int u = t - 128, b2 = u >> 3, k = u & 7;
    attb[b2 * 72 + k * 9 + 8] = 0.f;
  }
  __syncthreads();
  if (t < 16) {
    int b2 = t >> 3, k = t & 7;
    float* row = &attb[b2 * 72 + k * 9];
    float mx = row[0];
    for (int n = 1; n < 9; n++) mx = fmaxf(mx, row[n]);
    float e[9], ssum = 0.f;
    for (int n = 0; n < 9; n++) { e[n] = expf(row[n] - mx); ssum += e[n]; }
    for (int n = 0; n < 9; n++) row[n] = e[n] / ssum;
  }
  __syncthreads();
  if (t < 2) {
    bool taken[8] = {};
    for (int dd = 0; dd < 3; dd++) {
      int bi = 0; float bv = -1e30f;
      for (int k = 0; k < 8; k++) {
        float v = attb[t * 72 + k * 9 + 0];
        if (!taken[k] && v > bv) { bv = v; bi = k; }
      }
      taken[bi] = true;
    }
    for (int k = 0; k < 8; k++) m8_[t * 8 + k] = taken[k] ? 0.f : 1.f;
  }
  __syncthreads();
  for (int idx = t; idx < 2048; idx += 256) {
    int n16 = idx >> 7, j = idx & 127, b2 = n16 >> 3, k = n16 & 7;
    float a = 0.f;
#pragma unroll
    for (int n = 0; n < 8; n++) a += attb[b2 * 72 + k * 9 + n] * vsb[(b2 * 8 + n) * 128 + j];
    Xf[n16 * 132 + j] = a;
    out_mask[gbase + idx] = m8_[n16];
  }
  if (t < 16) { out_bm[n0 + t] = m8_[t]; mask8[n0 + t] = m8_[t]; }
  __syncthreads();
  // X-frag writer: unit = (ks, lane), value X[row=c15][k=ks*32+qd*8+j]
  for (int u = t; u < 512; u += 256) {
    int ks = u >> 6, lane = u & 63, c15 = lane & 15, qd = lane >> 4;
    int kb = ks * 32 + qd * 8;
    half8 hi, lo;
#pragma unroll
    for (int j = 0; j < 8; j++) {
      int k = kb + j;
      float v = (k < 128) ? Xf[c15 * 132 + k] : hxs[c15 * 128 + (k - 128)];
      half_t h = (half_t)v;
      hi[j] = h; lo[j] = (half_t)(v - (float)h);
    }
    size_t off = ((size_t)(blockIdx.x * 8 + ks) * 64 + lane) * 8;
    *reinterpret_cast<half8*>(xh + off) = hi;
    *reinterpret_cast<half8*>(xl + off) = lo;
  }
}

// ================= kB: gates GEMM + LSTM + selection =================
// 512 threads, 32 rows/block. Wave w: template m=w>>1, s-half sh=w&1.
// N split into 4 sequential c4-passes: acc[4][2]=32 VGPR, frees regs for
// load pipelining (round-6's acc[16][2]=128 VGPR starved the pipeliner).
__global__ __launch_bounds__(512, 2)
void kB(const int* __restrict__ flag, const half_t* __restrict__ wsp,
        const float* __restrict__ cx,
        const float* __restrict__ b_ih, const float* __restrict__ b_hh,
        const float* __restrict__ hread, const float* __restrict__ mask8,
        half_t* __restrict__ hbout, float* __restrict__ out_cx,
        float* __restrict__ out_ta)
{
  if (*flag != 0) return;
  const int t = threadIdx.x, lane = t & 63, w = t >> 6;
  const int m = w >> 1, sh = w & 1;
  const int c15 = lane & 15, qd = lane >> 4;
  const int n0 = blockIdx.x * 32;

  __shared__ __align__(16) half_t hth[32 * 520];
  __shared__ __align__(16) half_t htl[32 * 520];
  __shared__ float wks[2048];
  __shared__ float zb[128];
  __shared__ float m8s[32];
  __shared__ int msh[32];

  if (t < 32) m8s[t] = mask8[n0 + t];

  const half_t* xh = wsp + F_XH;
  const half_t* xl = wsp + F_XL;

  half_t ccr[4][2][4];   // c_t parked as f16 (cx-out precision ample)

  for (int c4 = 0; c4 < 4; c4++) {
    float4v acc[4][2];
#pragma unroll
    for (int g = 0; g < 4; g++)
#pragma unroll
      for (int mt = 0; mt < 2; mt++) acc[g][mt] = (float4v){0.f, 0.f, 0.f, 0.f};

    for (int ks = 0; ks < 8; ks++) {
      half8 ah[2], al[2];
#pragma unroll
      for (int mt = 0; mt < 2; mt++) {
        size_t aoff = ((size_t)((blockIdx.x * 2 + mt) * 8 + ks) * 64 + lane) * 8;
        ah[mt] = *reinterpret_cast<const half8*>(xh + aoff);
        al[mt] = *reinterpret_cast<const half8*>(xl + aoff);
      }
      half8 bh[4], bl[4];
#pragma unroll
      for (int g = 0; g < 4; g++) {
        int nt = g * 8 + sh * 4 + c4;
        size_t boff = ((size_t)((m * 32 + nt) * 8 + ks) * 64 + lane) * 8;
        bh[g] = *reinterpret_cast<const half8*>(wsp + F_GH + boff);
        bl[g] = *reinterpret_cast<const half8*>(wsp + F_GL + boff);
      }
#pragma unroll
      for (int g = 0; g < 4; g++)
#pragma unroll
        for (int mt = 0; mt < 2; mt++) {
          acc[g][mt] = MFMA16(ah[mt], bh[g], acc[g][mt]);
          acc[g][mt] = MFMA16(ah[mt], bl[g], acc[g][mt]);
          acc[g][mt] = MFMA16(al[mt], bh[g], acc[g][mt]);
        }
    }
    // ---- LSTM epilogue for this c4's columns ----
    int s = sh * 64 + c4 * 16 + c15;
    float bi = b_ih[m * 512 + s]       + b_hh[m * 512 + s];
    float bf = b_ih[m * 512 + 128 + s] + b_hh[m * 512 + 128 + s];
    float bg = b_ih[m * 512 + 256 + s] + b_hh[m * 512 + 256 + s];
    float bo = b_ih[m * 512 + 384 + s] + b_hh[m * 512 + 384 + s];
#pragma unroll
    for (int mt = 0; mt < 2; mt++) {
#pragma unroll
      for (int rg = 0; rg < 4; rg++) {
        int row = mt * 16 + qd * 4 + rg;
        float iv = acc[0][mt][rg] + bi;
        float fv = acc[1][mt][rg] + bf;
        float gv = acc[2][mt][rg] + bg;
        float ov = acc[3][mt][rg] + bo;
        float cxv = cx[(size_t)(n0 + row) * 128 + s];
        float cc = sigm(fv) * cxv + sigm(iv) * tanhf(gv);
        float hh = sigm(ov) * tanhf(cc);
        ccr[c4][mt][rg] = (half_t)cc;
        half_t hhi = (half_t)hh;
        hth[row * 520 + m * 128 + s] = hhi;
        htl[row * 520 + m * 128 + s] = (half_t)(hh - (float)hhi);
      }
    }
  }
  __syncthreads();
  // ---- write-key MFMA: wave w handles (m, row-tile sh) ----
  {
    float4v wa = (float4v){0.f, 0.f, 0.f, 0.f};
    const half_t* Wh = wsp + F_WWH + (m * 16 + c15) * 128 + qd * 8;
    const half_t* Wl = wsp + F_WWL + (m * 16 + c15) * 128 + qd * 8;
    const half_t* Hh = &hth[(sh * 16 + c15) * 520 + m * 128 + qd * 8];
    const half_t* Hl = &htl[(sh * 16 + c15) * 520 + m * 128 + qd * 8];
#pragma unroll
    for (int ks = 0; ks < 4; ks++) {
      half8 ahf = *reinterpret_cast<const half8*>(Hh + ks * 32);
      half8 alf = *reinterpret_cast<const half8*>(Hl + ks * 32);
      half8 bhf = *reinterpret_cast<const half8*>(Wh + ks * 32);
      half8 blf = *reinterpret_cast<const half8*>(Wl + ks * 32);
      wa = MFMA16(ahf, bhf, wa);
      wa = MFMA16(ahf, blf, wa);
      wa = MFMA16(alf, bhf, wa);
    }
#pragma unroll
    for (int rg = 0; rg < 4; rg++)
      wks[m * 512 + (sh * 16 + qd * 4 + rg) * 16 + c15] = wa[rg];
  }
  __syncthreads();
  if (t < 128) {
    int row = t >> 2, mm = t & 3;
    float lg = 0.f;
#pragma unroll
    for (int d = 0; d < 16; d++)
      lg += hread[(size_t)(n0 + row) * 16 + d] * wks[mm * 512 + row * 16 + d];
    zb[t] = lg + gumbel_at((unsigned)((n0 + row) * 4 + mm));
  }
  __syncthreads();
  if (t < 32) {
    int ms = 0; float best = zb[t * 4];
#pragma unroll
    for (int mm = 1; mm < 4; mm++)
      if (zb[t * 4 + mm] > best) { best = zb[t * 4 + mm]; ms = mm; }
    msh[t] = ms;
#pragma unroll
    for (int mm = 0; mm < 4; mm++)
      out_ta[(size_t)(n0 + t) * 4 + mm] = (mm == ms) ? 1.0f : 0.0f;
  }
  __syncthreads();
  // ---- cx out (owning wave m == msh[row]) ----
#pragma unroll
  for (int c4 = 0; c4 < 4; c4++) {
    int s = sh * 64 + c4 * 16 + c15;
#pragma unroll
    for (int mt = 0; mt < 2; mt++) {
#pragma unroll
      for (int rg = 0; rg < 4; rg++) {
        int row = mt * 16 + qd * 4 + rg;
        if (msh[row] == m) {
          float co = (m8s[row] != 0.f) ? (float)ccr[c4][mt][rg]
                                       : cx[(size_t)(n0 + row) * 128 + s];
          out_cx[(size_t)(n0 + row) * 128 + s] = co;
        }
      }
    }
  }
  // ---- hb out (plain f16 [row][s]) ----
  for (int idx = t; idx < 4096; idx += 512) {
    int r = idx >> 7, s = idx & 127;
    hbout[(size_t)(n0 + r) * 128 + s] = hth[r * 520 + msh[r] * 128 + s];
  }
}

// ================= kC: communication attention + final hx blend =============
__global__ __launch_bounds__(256)
void kC(const int* __restrict__ flag, const half_t* __restrict__ wsp,
        const half_t* __restrict__ hbin, const float* __restrict__ mask8,
        const float* __restrict__ hx,
        const float* __restrict__ bf_c, const float* __restrict__ bg_c,
        float* __restrict__ out_hx)
{
  if (*flag != 0) return;
  const int t = threadIdx.x;
  const int n0 = blockIdx.x * 16;
  const int lane = t & 63, wv = t >> 6;
  const int col15 = lane & 15, quad = lane >> 4;

  __shared__ __align__(16) half_t hbF[2176], qcF[2176], kcF[2176], vcF[2176], oF[2176];
  __shared__ float attb[512];
  __shared__ float m8s[16];

  {
    int r = t >> 4, c8 = t & 15;
    *reinterpret_cast<half8*>(&hbF[r * 136 + c8 * 8]) =
        *reinterpret_cast<const half8*>(hbin + (size_t)(n0 + r) * 128 + c8 * 8);
  }
  if (t < 16) m8s[t] = mask8[n0 + t];
  __syncthreads();

  if (wv < 3) {
    float4v pacc[8];
#pragma unroll
    for (int ct = 0; ct < 8; ct++) pacc[ct] = (float4v){0.f, 0.f, 0.f, 0.f};
    const half_t* Bp = wsp + F_CQ + wv * 16384 + col15 * 128 + quad * 8;
    const half_t* Ap = &hbF[col15 * 136 + quad * 8];
#pragma unroll
    for (int ks = 0; ks < 4; ks++) {
      half8 a = *reinterpret_cast<const half8*>(Ap + ks * 32);
#pragma unroll
      for (int ct = 0; ct < 8; ct++) {
        half8 b = *reinterpret_cast<const half8*>(Bp + ct * 2048 + ks * 32);
        pacc[ct] = MFMA16(a, b, pacc[ct]);
      }
    }
    half_t* dst = (wv == 0) ? qcF : (wv == 1) ? kcF : vcF;
#pragma unroll
    for (int ct = 0; ct < 8; ct++)
#pragma unroll
      for (int rg = 0; rg < 4; rg++)
        dst[(quad * 4 + rg) * 136 + ct * 16 + col15] = (half_t)pacc[ct][rg];
  }
  __syncthreads();

  if (t < 64) {
    int b2 = t >> 5, h = (t >> 3) & 3, q = t & 7;
    float sc[8];
#pragma unroll
    for (int kq = 0; kq < 8; kq++) {
      float a = 0.f;
#pragma unroll
      for (int d = 0; d < 32; d++)
        a += (float)qcF[(b2 * 8 + q) * 136 + h * 32 + d] *
             (float)kcF[(b2 * 8 + kq) * 136 + h * 32 + d];
      sc[kq] = a * 0.17677669529663688110f;
    }
    float mx = sc[0];
#pragma unroll
    for (int kq = 1; kq < 8; kq++) mx = fmaxf(mx, sc[kq]);
    float e[8], ssum = 0.f;
#pragma unroll
    for (int kq = 0; kq < 8; kq++) { e[kq] = expf(sc[kq] - mx); ssum += e[kq]; }
#pragma unroll
    for (int kq = 0; kq < 8; kq++)
      attb[((b2 * 4 + h) * 8 + q) * 8 + kq] = e[kq] / ssum;
  }
  __syncthreads();

  for (int idx = t; idx < 2048; idx += 256) {
    int r = idx >> 7, cn = idx & 127, b2 = r >> 3, q = r & 7, h = cn >> 5;
    float a = 0.f;
#pragma unroll
    for (int kq = 0; kq < 8; kq++)
      a += attb[((b2 * 4 + h) * 8 + q) * 8 + kq] * (float)vcF[(b2 * 8 + kq) * 136 + cn];
    oF[r * 136 + cn] = (half_t)a;
  }
  __syncthreads();

  {
    float4v fa[2], ga[2];
#pragma unroll
    for (int tt = 0; tt < 2; tt++) {
      fa[tt] = (float4v){0.f, 0.f, 0.f, 0.f};
      ga[tt] = (float4v){0.f, 0.f, 0.f, 0.f};
    }
    const half_t* Ao = &oF[col15 * 136 + quad * 8];
    const half_t* Bf = wsp + F_CQ + 3 * 16384 + (wv * 32 + col15) * 128 + quad * 8;
    const half_t* Bg = wsp + F_CQ + 4 * 16384 + (wv * 32 + col15) * 128 + quad * 8;
#pragma unroll
    for (int ks = 0; ks < 4; ks++) {
      half8 a = *reinterpret_cast<const half8*>(Ao + ks * 32);
#pragma unroll
      for (int tt = 0; tt < 2; tt++) {
        half8 bfv = *reinterpret_cast<const half8*>(Bf + tt * 2048 + ks * 32);
        half8 bgv = *reinterpret_cast<const half8*>(Bg + tt * 2048 + ks * 32);
        fa[tt] = MFMA16(a, bfv, fa[tt]);
        ga[tt] = MFMA16(a, bgv, ga[tt]);
      }
    }
#pragma unroll
    for (int tt = 0; tt < 2; tt++) {
      int col = wv * 32 + tt * 16 + col15;
      float bfb = bf_c[col], bgb = bg_c[col];
#pragma unroll
      for (int rg = 0; rg < 4; rg++) {
        int row = quad * 4 + rg;
        float af = fa[tt][rg] + bfb;
        float ag = ga[tt][rg] + bgb;
        float comm = sigm(ag) * tanhf(af);
        float hbv = (float)hbF[row * 136 + col];
        float hv = (m8s[row] != 0.f) ? (hbv + comm)
                                     : hx[(size_t)(n0 + row) * 128 + col];
        out_hx[(size_t)(n0 + row) * 128 + col] = hv;
      }
    }
  }
}

// ================= tier-2 (round-5) kernels, kept as fallback =================
__global__ __launch_bounds__(256)
void k_wsplit(const float* __restrict__ W_ih, const float* __restrict__ W_hh,
              const float* __restrict__ W_write,
              const float* __restrict__ Wq_c, const float* __restrict__ Wk_c,
              const float* __restrict__ Wv_c, const float* __restrict__ Wf_c,
              const float* __restrict__ Wg_c, half_t* __restrict__ ws) {
  int i = blockIdx.x * 256 + threadIdx.x;
  if (i < 524288) {
    int n = i >> 8, k = i & 255;
    int m = n >> 9, g = n & 511;
    float w = (k < 128) ? W_ih[(m * 512 + g) * 128 + k]
                        : W_hh[(m * 512 + g) * 128 + (k - 128)];
    half_t h = (half_t)w;
    ws[GH + i] = h;
    ws[GL + i] = (half_t)(w - (float)h);
  } else if (i < 532480) {
    int j = i - 524288; int md = j >> 7, s = j & 127; int m = md >> 4, d = md & 15;
    float w = W_write[(m * 128 + s) * 16 + d];
    half_t h = (half_t)w;
    ws[WWH + j] = h;
    ws[WWL + j] = (half_t)(w - (float)h);
  } else if (i < 614400) {
    int j = i - 532480; int which = j >> 14, r = j & 16383;
    int col = r >> 7, k = r & 127;
    const float* Wsel = which == 0 ? Wq_c : which == 1 ? Wk_c :
                        which == 2 ? Wv_c : which == 3 ? Wf_c : Wg_c;
    ws[CQ + which * 16384 + r] = (half_t)Wsel[k * 128 + col];
  }
}

__global__ __launch_bounds__(256)
void k_scoff_mfma(const int* __restrict__ flag, const half_t* __restrict__ wsp,
                  const float* __restrict__ inp, const float* __restrict__ hx,
                  const float* __restrict__ cx,
                  const float* __restrict__ Wq_i, const float* __restrict__ Wk_i,
                  const float* __restrict__ Wv_i,
                  const float* __restrict__ bf_c, const float* __restrict__ bg_c,
                  const float* __restrict__ b_ih, const float* __restrict__ b_hh,
                  const float* __restrict__ W_read,
                  float* __restrict__ out_hx, float* __restrict__ out_cx,
                  float* __restrict__ out_mask, float* __restrict__ out_bm,
                  float* __restrict__ out_ta)
{
  if (*flag != 0) return;

  const int t = threadIdx.x;
  const int n0 = blockIdx.x * 16, gbase = n0 * 128;
  const int lane = t & 63, wv = t >> 6;
  const int col15 = lane & 15, quad = lane >> 4;

  __shared__ __align__(16) float hxs[2048];
  __shared__ __align__(16) float cxs[2048];
  __shared__ __align__(16) float vsb[2048];
  __shared__ float qsb[1088], kslb[1088];
  __shared__ __align__(16) half_t sXh[16 * 264];
  __shared__ __align__(16) half_t sXl[16 * 264];
  __shared__ __align__(16) half_t hth[16 * 520];
  __shared__ __align__(16) half_t htl[16 * 520];
  __shared__ __align__(16) half_t cts[16 * 512];
  __shared__ float wks[1024];
  __shared__ __align__(16) half_t hbF[16 * 136];
  __shared__ __align__(16) half_t oF[16 * 136];
  __shared__ __align__(16) half_t qcF[16 * 136];
  __shared__ __align__(16) half_t kcF[16 * 136];
  __shared__ __align__(16) half_t vcF[16 * 136];
  __shared__ float attb[512];
  __shared__ float hrs_[256];
  __shared__ float zbuf[64];
  __shared__ float m8_[16];
  __shared__ int   msh_[16];

  for (int idx = t; idx < 512; idx += 256) {
    *reinterpret_cast<float4*>(&hxs[idx * 4]) =
        *reinterpret_cast<const float4*>(hx + gbase + idx * 4);
    *reinterpret_cast<float4*>(&cxs[idx * 4]) =
        *reinterpret_cast<const float4*>(cx + gbase + idx * 4);
  }
  {
    __shared__ __align__(16) float inps[2048];
    for (int idx = t; idx < 512; idx += 256)
      *reinterpret_cast<float4*>(&inps[idx * 4]) =
          *reinterpret_cast<const float4*>(inp + gbase + idx * 4);
    __syncthreads();
    for (int idx = t; idx < 1024; idx += 256) {
      int k16 = idx >> 6, d = idx & 63;
      float aq = 0.f, ak = 0.f;
#pragma unroll 8
      for (int i = 0; i < 128; i++) {
        aq += hxs[k16 * 128 + i]  * Wq_i[i * 64 + d];
        ak += inps[k16 * 128 + i] * Wk_i[i * 64 + d];
      }
      qsb[k16 * 68 + d] = aq; kslb[k16 * 68 + d] = ak;
    }
    for (int idx = t; idx < 2048; idx += 256) {
      int n16 = idx >> 7, j = idx & 127;
      float a = 0.f;
#pragma unroll 8
      for (int i = 0; i < 128; i++) a += inps[n16 * 128 + i] * Wv_i[i * 128 + j];
      vsb[idx] = a;
    }
  }
  {
    int n16 = t >> 4, d = t & 15;
    float a = 0.f;
#pragma unroll 8
    for (int i = 0; i < 128; i++) a += hxs[n16 * 128 + i] * W_read[i * 16 + d];
    hrs_[t] = a;
  }
  for (int idx = t; idx < 2048; idx += 256) {
    int r = idx >> 7, i = idx & 127;
    float v = hxs[r * 128 + i];
    half_t hh = (half_t)v;
    sXh[r * 264 + 128 + i] = hh;
    sXl[r * 264 + 128 + i] = (half_t)(v - (float)hh);
  }
  __syncthreads();

  if (t < 128) {
    int b2 = t >> 6, k = (t >> 3) & 7, n = t & 7;
    float sc = 0.f;
#pragma unroll
    for (int d = 0; d < 64; d++)
      sc += qsb[(b2 * 8 + k) * 68 + d] * kslb[(b2 * 8 + n) * 68 + d];
    attb[b2 * 72 + k * 9 + n] = sc * 0.125f;
  } else if (t < 144) {
    int u = t - 128, b2 = u >> 3, k = u & 7;
    attb[b2 * 72 + k * 9 + 8] = 0.f;
  }
  __syncthreads();
  if (t < 16) {
    int b2 = t >> 3, k = t & 7;
    float* row = &attb[b2 * 72 + k * 9];
    float mx = row[0];
    for (int n = 1; n < 9; n++) mx = fmaxf(mx, row[n]);
    float e[9], ssum = 0.f;
    for (int n = 0; n < 9; n++) { e[n] = expf(row[n] - mx); ssum += e[n]; }
    for (int n = 0; n < 9; n++) row[n] = e[n] / ssum;
  }
  __syncthreads();
  if (t < 2) {
    bool taken[8] = {};
    for (int dd = 0; dd < 3; dd++) {
      int bi = 0; float bv = -1e30f;
      for (int k = 0; k < 8; k++) {
        float v = attb[t * 72 + k * 9 + 0];
        if (!taken[k] && v > bv) { bv = v; bi = k; }
      }
      taken[bi] = true;
    }
    for (int k = 0; k < 8; k++) m8_[t * 8 + k] = taken[k] ? 0.f : 1.f;
  }
  __syncthreads();
  for (int idx = t; idx < 2048; idx += 256) {
    int n16 = idx >> 7, j = idx & 127, b2 = n16 >> 3, k = n16 & 7;
    float a = 0.f;
#pragma unroll
    for (int n = 0; n < 8; n++) a += attb[b2 * 72 + k * 9 + n] * vsb[(b2 * 8 + n) * 128 + j];
    half_t hh = (half_t)a;
    sXh[n16 * 264 + j] = hh;
    sXl[n16 * 264 + j] = (half_t)(a - (float)hh);
    out_mask[gbase + idx] = m8_[n16];
  }
  if (t < 16) out_bm[n0 + t] = m8_[t];
  __syncthreads();
  for (int idx = t; idx < 2048; idx += 256) vsb[idx] = b_ih[idx] + b_hh[idx];
  __syncthreads();

  {
    float4v acc[32];
#pragma unroll
    for (int ct = 0; ct < 32; ct++) acc[ct] = (float4v){0.f, 0.f, 0.f, 0.f};
    const half_t* Ah = &sXh[col15 * 264 + quad * 8];
    const half_t* Al = &sXl[col15 * 264 + quad * 8];
    const half_t* Bh = wsp + GH + (size_t)(wv * 512 + col15) * 256 + quad * 8;
    const half_t* Bl = wsp + GL + (size_t)(wv * 512 + col15) * 256 + quad * 8;
    for (int ks = 0; ks < 8; ks++) {
      half8 ah = *reinterpret_cast<const half8*>(Ah + ks * 32);
      half8 al = *reinterpret_cast<const half8*>(Al + ks * 32);
#pragma unroll
      for (int ct = 0; ct < 32; ct++) {
        half8 bh = *reinterpret_cast<const half8*>(Bh + ct * 4096 + ks * 32);
        half8 bl = *reinterpret_cast<const half8*>(Bl + ct * 4096 + ks * 32);
        acc[ct] = MFMA16(ah, bh, acc[ct]);
        acc[ct] = MFMA16(ah, bl, acc[ct]);
        acc[ct] = MFMA16(al, bh, acc[ct]);
      }
    }
#pragma unroll
    for (int sh = 0; sh < 8; sh++) {
      int s = sh * 16 + col15;
      float bi = vsb[wv * 512 + s];
      float bf = vsb[wv * 512 + 128 + s];
      float bg = vsb[wv * 512 + 256 + s];
      float bo = vsb[wv * 512 + 384 + s];
#pragma unroll
      for (int rg = 0; rg < 4; rg++) {
        int row = quad * 4 + rg;
        float iv = acc[sh][rg] + bi;
        float fv = acc[8 + sh][rg] + bf;
        float gv = acc[16 + sh][rg] + bg;
        float ov = acc[24 + sh][rg] + bo;
        float cc = sigm(fv) * cxs[row * 128 + s] + sigm(iv) * tanhf(gv);
        float hh = sigm(ov) * tanhf(cc);
        half_t hhi = (half_t)hh;
        hth[row * 520 + wv * 128 + s] = hhi;
        htl[row * 520 + wv * 128 + s] = (half_t)(hh - (float)hhi);
        cts[row * 512 + wv * 128 + s] = (half_t)cc;
      }
    }
  }
  __syncthreads();

  {
    float4v wacc = (float4v){0.f, 0.f, 0.f, 0.f};
    const half_t* Wh = wsp + WWH + (wv * 16 + col15) * 128 + quad * 8;
    const half_t* Wl = wsp + WWL + (wv * 16 + col15) * 128 + quad * 8;
    const half_t* Hh = &hth[col15 * 520 + wv * 128 + quad * 8];
    const half_t* Hl = &htl[col15 * 520 + wv * 128 + quad * 8];
#pragma unroll
    for (int ks = 0; ks < 4; ks++) {
      half8 ah = *reinterpret_cast<const half8*>(Hh + ks * 32);
      half8 al = *reinterpret_cast<const half8*>(Hl + ks * 32);
      half8 bh = *reinterpret_cast<const half8*>(Wh + ks * 32);
      half8 bl = *reinterpret_cast<const half8*>(Wl + ks * 32);
      wacc = MFMA16(ah, bh, wacc);
      wacc = MFMA16(ah, bl, wacc);
      wacc = MFMA16(al, bh, wacc);
    }
#pragma unroll
    for (int rg = 0; rg < 4; rg++)
      wks[wv * 256 + (quad * 4 + rg) * 16 + col15] = wacc[rg];
  }
  __syncthreads();
  if (t < 64) {
    int row = t >> 2, mm = t & 3;
    float lg = 0.f;
#pragma unroll
    for (int d = 0; d < 16; d++) lg += hrs_[row * 16 + d] * wks[mm * 256 + row * 16 + d];
    zbuf[t] = lg + gumbel_at((unsigned)((n0 + row) * 4 + mm));
  }
  __syncthreads();
  if (t < 16) {
    int ms = 0; float best = zbuf[t * 4];
#pragma unroll
    for (int m = 1; m < 4; m++)
      if (zbuf[t * 4 + m] > best) { best = zbuf[t * 4 + m]; ms = m; }
    msh_[t] = ms;
#pragma unroll
    for (int m = 0; m < 4; m++) out_ta[(n0 + t) * 4 + m] = (m == ms) ? 1.0f : 0.0f;
  }
  __syncthreads();
  for (int idx = t; idx < 2048; idx += 256) {
    int r = idx >> 7, s = idx & 127;
    float cv = (float)cts[r * 512 + msh_[r] * 128 + s];
    out_cx[gbase + idx] = (m8_[r] != 0.f) ? cv : cxs[idx];
    hbF[r * 136 + s] = hth[r * 520 + msh_[r] * 128 + s];
  }
  __syncthreads();

  if (wv < 3) {
    float4v pacc[8];
#pragma unroll
    for (int ct = 0; ct < 8; ct++) pacc[ct] = (float4v){0.f, 0.f, 0.f, 0.f};
    const half_t* Bp = wsp + CQ + wv * 16384 + col15 * 128 + quad * 8;
    const half_t* Ap = &hbF[col15 * 136 + quad * 8];
#pragma unroll
    for (int ks = 0; ks < 4; ks++) {
      half8 a = *reinterpret_cast<const half8*>(Ap + ks * 32);
#pragma unroll
      for (int ct = 0; ct < 8; ct++) {
        half8 b = *reinterpret_cast<const half8*>(Bp + ct * 2048 + ks * 32);
        pacc[ct] = MFMA16(a, b, pacc[ct]);
      }
    }
    half_t* dst = (wv == 0) ? qcF : (wv == 1) ? kcF : vcF;
#pragma unroll
    for (int ct = 0; ct < 8; ct++)
#pragma unroll
      for (int rg = 0; rg < 4; rg++)
        dst[(quad * 4 + rg) * 136 + ct * 16 + col15] = (half_t)pacc[ct][rg];
  }
  __syncthreads();

  if (t < 64) {
    int b2 = t >> 5, h = (t >> 3) & 3, q = t & 7;
    float sc[8];
#pragma unroll
    for (int kq = 0; kq < 8; kq++) {
      float a = 0.f;
#pragma unroll
      for (int d = 0; d < 32; d++)
        a += (float)qcF[(b2 * 8 + q) * 136 + h * 32 + d] *
             (float)kcF[(b2 * 8 + kq) * 136 + h * 32 + d];
      sc[kq] = a * 0.17677669529663688110f;
    }
    float mx = sc[0];
#pragma unroll
    for (int kq = 1; kq < 8; kq++) mx = fmaxf(mx, sc[kq]);
    float e[8], ssum = 0.f;
#pragma unroll
    for (int kq = 0; kq < 8; kq++) { e[kq] = expf(sc[kq] - mx); ssum += e[kq]; }
#pragma unroll
    for (int kq = 0; kq < 8; kq++)
      attb[((b2 * 4 + h) * 8 + q) * 8 + kq] = e[kq] / ssum;
  }
  __syncthreads();

  for (int idx = t; idx < 2048; idx += 256) {
    int r = idx >> 7, cn = idx & 127, b2 = r >> 3, q = r & 7, h = cn >> 5;
    float a = 0.f;
#pragma unroll
    for (int kq = 0; kq < 8; kq++)
      a += attb[((b2 * 4 + h) * 8 + q) * 8 + kq] * (float)vcF[(b2 * 8 + kq) * 136 + cn];
    oF[r * 136 + cn] = (half_t)a;
  }
  __syncthreads();

  {
    float4v fa[2], ga[2];
#pragma unroll
    for (int tt = 0; tt < 2; tt++) {
      fa[tt] = (float4v){0.f, 0.f, 0.f, 0.f};
      ga[tt] = (float4v){0.f, 0.f, 0.f, 0.f};
    }
    const half_t* Ao = &oF[col15 * 136 + quad * 8];
    const half_t* Bf = wsp + CF + (wv * 32 + col15) * 128 + quad * 8;
    const half_t* Bg = wsp + CG + (wv * 32 + col15) * 128 + quad * 8;
#pragma unroll
    for (int ks = 0; ks < 4; ks++) {
      half8 a = *reinterpret_cast<const half8*>(Ao + ks * 32);
#pragma unroll
      for (int tt = 0; tt < 2; tt++) {
        half8 bf = *reinterpret_cast<const half8*>(Bf + tt * 2048 + ks * 32);
        half8 bg = *reinterpret_cast<const half8*>(Bg + tt * 2048 + ks * 32);
        fa[tt] = MFMA16(a, bf, fa[tt]);
        ga[tt] = MFMA16(a, bg, ga[tt]);
      }
    }
#pragma unroll
    for (int tt = 0; tt < 2; tt++) {
      int col = wv * 32 + tt * 16 + col15;
      float bfv = bf_c[col], bgv = bg_c[col];
#pragma unroll
      for (int rg = 0; rg < 4; rg++) {
        int row = quad * 4 + rg;
        float af = fa[tt][rg] + bfv;
        float ag = ga[tt][rg] + bgv;
        float comm = sigm(ag) * tanhf(af);
        float hb = (float)hth[row * 520 + msh_[row] * 128 + col] +
                   (float)htl[row * 520 + msh_[row] * 128 + col];
        float hv = (m8_[row] != 0.f) ? (hb + comm)
                                     : hx[(size_t)(n0 + row) * 128 + col];
        out_hx[(size_t)(n0 + row) * 128 + col] = hv;
      }
    }
  }
}

// ================= tier-3: round-4 VALU kernels (f32 / bf16) =================
template<int MODE> struct IO;
template<> struct IO<0> {
  static __device__ __forceinline__ float ld(const void* p, int i) { return ((const float*)p)[i]; }
  static __device__ __forceinline__ void st(void* p, int i, float v) { ((float*)p)[i] = v; }
};
template<> struct IO<1> {
  static __device__ __forceinline__ float ld(const void* p, int i) {
    return __bfloat162float(((const bf16*)p)[i]);
  }
  static __device__ __forceinline__ void st(void* p, int i, float v) {
    ((bf16*)p)[i] = __float2bfloat16(v);
  }
};

template<int MODE>
__global__ __launch_bounds__(256, 2)
void k_scoff(const int* __restrict__ flag,
             const void* __restrict__ inp, const void* __restrict__ hx,
             const void* __restrict__ cx,
             const void* __restrict__ Wq_i, const void* __restrict__ Wk_i,
             const void* __restrict__ Wv_i,
             const void* __restrict__ Wq_c, const void* __restrict__ Wk_c,
             const void* __restrict__ Wv_c, const void* __restrict__ Wf_c,
             const void* __restrict__ bf_c, const void* __restrict__ Wg_c,
             const void* __restrict__ bg_c,
             const void* __restrict__ W_ih, const void* __restrict__ W_hh,
             const void* __restrict__ b_ih, const void* __restrict__ b_hh,
             const void* __restrict__ W_read, const void* __restrict__ W_write,
             void* __restrict__ out_hx, void* __restrict__ out_cx,
             void* __restrict__ out_mask, void* __restrict__ out_bm,
             void* __restrict__ out_ta)
{
  if (*flag != MODE) return;

  const int t  = threadIdx.x;
  const int n0 = blockIdx.x * 16;
  const int gbase = n0 * 128;

  __shared__ float inps_os[2048];
  __shared__ float As[4096];
  __shared__ float Bs[8320];
  __shared__ float attbuf[512];
  __shared__ float hrs[256];
  __shared__ float m8[16];
  __shared__ int   msh[16];

  float* const qs  = Bs;
  float* const ksl = Bs + 1024;
  float* const vs  = Bs + 2048;
  float* const hxs = Bs + 4096;

  if constexpr (MODE == 1) {
    const unsigned* hx32 = (const unsigned*)((const bf16*)hx + gbase);
    const unsigned* in32 = (const unsigned*)((const bf16*)inp + gbase);
    for (int idx = t; idx < 1024; idx += 256) {
      unsigned wh = hx32[idx], wi = in32[idx];
      hxs[2 * idx]         = __uint_as_float(wh << 16);
      hxs[2 * idx + 1]     = __uint_as_float(wh & 0xffff0000u);
      inps_os[2 * idx]     = __uint_as_float(wi << 16);
      inps_os[2 * idx + 1] = __uint_as_float(wi & 0xffff0000u);
    }
  } else {
    const float* hxf = (const float*)hx + gbase;
    const float* inf_ = (const float*)inp + gbase;
    for (int idx = t; idx < 512; idx += 256) {
      *reinterpret_cast<float4*>(&hxs[idx * 4]) =
          *reinterpret_cast<const float4*>(hxf + idx * 4);
      *reinterpret_cast<float4*>(&inps_os[idx * 4]) =
          *reinterpret_cast<const float4*>(inf_ + idx * 4);
    }
  }
  __syncthreads();

  for (int idx = t; idx < 1024; idx += 256) {
    int k16 = idx >> 6, d = idx & 63;
    float aq = 0.f, ak = 0.f;
#pragma unroll 8
    for (int i = 0; i < 128; i++) {
      aq += hxs[k16 * 128 + i]     * IO<MODE>::ld(Wq_i, i * 64 + d);
      ak += inps_os[k16 * 128 + i] * IO<MODE>::ld(Wk_i, i * 64 + d);
    }
    qs[idx] = aq; ksl[idx] = ak;
  }
  for (int idx = t; idx < 2048; idx += 256) {
    int n16 = idx >> 7, j = idx & 127;
    float a = 0.f;
#pragma unroll 8
    for (int i = 0; i < 128; i++) a += inps_os[n16 * 128 + i] * IO<MODE>::ld(Wv_i, i * 128 + j);
    vs[idx] = a;
  }
  for (int idx = t; idx < 2048; idx += 256) {
    int i = idx >> 4, r = idx & 15;
    As[(128 + i) * 16 + r] = hxs[r * 128 + i];
  }
  {
    int n16 = t >> 4, d = t & 15;
    float a = 0.f;
#pragma unroll 8
    for (int i = 0; i < 128; i++) a += hxs[n16 * 128 + i] * IO<MODE>::ld(W_read, i * 16 + d);
    hrs[t] = a;
  }
  __syncthreads();

  if (t < 128) {
    int b2 = t >> 6, k = (t >> 3) & 7, n = t & 7;
    float sc = 0.f;
#pragma unroll
    for (int d = 0; d < 64; d++) sc += qs[(b2 * 8 + k) * 64 + d] * ksl[(b2 * 8 + n) * 64 + d];
    attbuf[b2 * 72 + k * 9 + n] = sc * 0.125f;
  } else if (t < 144) {
    int u = t - 128, b2 = u >> 3, k = u & 7;
    attbuf[b2 * 72 + k * 9 + 8] = 0.f;
  }
  __syncthreads();
  if (t < 16) {
    int b2 = t >> 3, k = t & 7;
    float* row = &attbuf[b2 * 72 + k * 9];
    float mx = row[0];
    for (int n = 1; n < 9; n++) mx = fmaxf(mx, row[n]);
    float e[9], ssum = 0.f;
    for (int n = 0; n < 9; n++) { e[n] = expf(row[n] - mx); ssum += e[n]; }
    for (int n = 0; n < 9; n++) row[n] = e[n] / ssum;
  }
  __syncthreads();
  if (t < 2) {
    bool taken[8] = {};
    for (int dd = 0; dd < 3; dd++) {
      int bi = 0; float bv = -1e30f;
      for (int k = 0; k < 8; k++) {
        float v = attbuf[t * 72 + k * 9 + 0];
        if (!taken[k] && v > bv) { bv = v; bi = k; }
      }
      taken[bi] = true;
    }
    for (int k = 0; k < 8; k++) m8[t * 8 + k] = taken[k] ? 0.f : 1.f;
  }
  __syncthreads();
  for (int idx = t; idx < 2048; idx += 256) {
    int n16 = idx >> 7, j = idx & 127, b2 = n16 >> 3, k = n16 & 7;
    float a = 0.f;
#pragma unroll
    for (int n = 0; n < 8; n++) a += attbuf[b2 * 72 + k * 9 + n] * vs[(b2 * 8 + n) * 128 + j];
    As[j * 16 + n16] = a;
    IO<MODE>::st(out_mask, gbase + idx, m8[n16]);
  }
  if (t < 16) IO<MODE>::st(out_bm, n0 + t, m8[t]);
  __syncthreads();

  const int s = t & 127, rg = t >> 7;
  float cvals[8];
#pragma unroll
  for (int j = 0; j < 8; j++) cvals[j] = IO<MODE>::ld(cx, (n0 + rg * 8 + j) * 128 + s);

  float ht[8][4], ct[8][4];
  const int sq = t >> 1, hf = t & 1;

#pragma unroll
  for (int m = 0; m < 4; m++) {
    float acc[8][4];
#pragma unroll
    for (int j = 0; j < 8; j++)
#pragma unroll
      for (int q = 0; q < 4; q++) acc[j][q] = 0.f;

    for (int kc = 0; kc < 256; kc += 16) {
      __syncthreads();
      {
        const int kb = (kc & 127) + hf * 8;
        float e[4][8];
        if constexpr (MODE == 1) {
          const bf16* Wsrc = (const bf16*)((kc < 128) ? W_ih : W_hh);
          uint4 wq[4];
#pragma unroll
          for (int q = 0; q < 4; q++)
            wq[q] = *reinterpret_cast<const uint4*>(Wsrc + ((m * 512 + q * 128 + sq) << 7) + kb);
#pragma unroll
          for (int q = 0; q < 4; q++) {
            unsigned w0 = wq[q].x, w1 = wq[q].y, w2 = wq[q].z, w3 = wq[q].w;
            e[q][0] = __uint_as_float(w0 << 16); e[q][1] = __uint_as_float(w0 & 0xffff0000u);
            e[q][2] = __uint_as_float(w1 << 16); e[q][3] = __uint_as_float(w1 & 0xffff0000u);
            e[q][4] = __uint_as_float(w2 << 16); e[q][5] = __uint_as_float(w2 & 0xffff0000u);
            e[q][6] = __uint_as_float(w3 << 16); e[q][7] = __uint_as_float(w3 & 0xffff0000u);
          }
        } else {
          const float* Wsrc = (const float*)((kc < 128) ? W_ih : W_hh);
#pragma unroll
          for (int q = 0; q < 4; q++) {
            const float* rowp = Wsrc + ((m * 512 + q * 128 + sq) << 7) + kb;
            float4 lo = *reinterpret_cast<const float4*>(rowp);
            float4 hi = *reinterpret_cast<const float4*>(rowp + 4);
            e[q][0] = lo.x; e[q][1] = lo.y; e[q][2] = lo.z; e[q][3] = lo.w;
            e[q][4] = hi.x; e[q][5] = hi.y; e[q][6] = hi.z; e[q][7] = hi.w;
          }
        }
#pragma unroll
        for (int c = 0; c < 8; c++) {
          float4 v; v.x = e[0][c]; v.y = e[1][c]; v.z = e[2][c]; v.w = e[3][c];
          *reinterpret_cast<float4*>(&Bs[(hf * 8 + c) * 520 + sq * 4]) = v;
        }
      }
      __syncthreads();
#pragma unroll
      for (int kk = 0; kk < 16; kk++) {
        const float4* ap = reinterpret_cast<const float4*>(&As[(kc + kk) * 16 + rg * 8]);
        float4 a0 = ap[0], a1 = ap[1];
        float4 bb = *reinterpret_cast<const float4*>(&Bs[kk * 520 + s * 4]);
        float av[8] = {a0.x, a0.y, a0.z, a0.w, a1.x, a1.y, a1.z, a1.w};
#pragma unroll
        for (int j = 0; j < 8; j++) {
          acc[j][0] += av[j] * bb.x;
          acc[j][1] += av[j] * bb.y;
          acc[j][2] += av[j] * bb.z;
          acc[j][3] += av[j] * bb.w;
        }
      }
    }
    float badd[4];
#pragma unroll
    for (int q = 0; q < 4; q++)
      badd[q] = IO<MODE>::ld(b_ih, m * 512 + q * 128 + s) +
                IO<MODE>::ld(b_hh, m * 512 + q * 128 + s);
#pragma unroll
    for (int j = 0; j < 8; j++) {
      float ig = acc[j][0] + badd[0];
      float fg = acc[j][1] + badd[1];
      float gg = acc[j][2] + badd[2];
      float og = acc[j][3] + badd[3];
      float c_t = sigm(fg) * cvals[j] + sigm(ig) * tanhf(gg);
      float h_t = sigm(og) * tanhf(c_t);
      ct[j][m] = c_t; ht[j][m] = h_t;
    }
  }

  __syncthreads();
#pragma unroll
  for (int j = 0; j < 8; j++) {
    int r = rg * 8 + j;
#pragma unroll
    for (int m = 0; m < 4; m++) Bs[r * 520 + m * 128 + s] = ht[j][m];
  }
  __syncthreads();
  {
    const int row = t >> 4, d = t & 15;
    const float hr = hrs[t];
    float lg[4];
#pragma unroll
    for (int m = 0; m < 4; m++) {
      float wk = 0.f;
#pragma unroll 8
      for (int ss = 0; ss < 128; ss++)
        wk += Bs[row * 520 + m * 128 + ss] * IO<MODE>::ld(W_write, (m * 128 + ss) * 16 + d);
      float p = hr * wk;
      p += __shfl_xor(p, 1, 64);
      p += __shfl_xor(p, 2, 64);
      p += __shfl_xor(p, 4, 64);
      p += __shfl_xor(p, 8, 64);
      lg[m] = p;
    }
    if (d == 0) {
      const int n = n0 + row;
      float z[4];
#pragma unroll
      for (int m = 0; m < 4; m++) z[m] = lg[m] + gumbel_at((unsigned)(n * 4 + m));
      int ms = 0; float best = z[0];
#pragma unroll
      for (int m = 1; m < 4; m++) if (z[m] > best) { best = z[m]; ms = m; }
      msh[row] = ms;
#pragma unroll
      for (int m = 0; m < 4; m++)
        IO<MODE>::st(out_ta, n * 4 + m, (m == ms) ? 1.0f : 0.0f);
    }
  }
  __syncthreads();
#pragma unroll
  for (int j = 0; j < 8; j++) {
    int r = rg * 8 + j;
    int ms = msh[r];
    float cv = ct[j][0];
    if (ms == 1) cv = ct[j][1];
    else if (ms == 2) cv = ct[j][2];
    else if (ms == 3) cv = ct[j][3];
    float co = (m8[r] != 0.f) ? cv : cvals[j];
    IO<MODE>::st(out_cx, (n0 + r) * 128 + s, co);
  }

  __syncthreads();
  for (int idx = t; idx < 2048; idx += 256) {
    int r = idx >> 7, col = idx & 127;
    As[idx] = Bs[r * 520 + msh[r] * 128 + col];
  }
  __syncthreads();
  for (int idx = t; idx < 2048; idx += 256) {
    int r = idx >> 7, col = idx & 127;
    float aq = 0.f, ak = 0.f, av = 0.f;
#pragma unroll 8
    for (int i = 0; i < 128; i++) {
      float h = As[r * 128 + i];
      aq += h * IO<MODE>::ld(Wq_c, i * 128 + col);
      ak += h * IO<MODE>::ld(Wk_c, i * 128 + col);
      av += h * IO<MODE>::ld(Wv_c, i * 128 + col);
    }
    Bs[idx] = aq; Bs[2048 + idx] = ak; Bs[4096 + idx] = av;
  }
  __syncthreads();
  if (t < 64) {
    int b2 = t >> 5, h = (t >> 3) & 3, q = t & 7;
    float sc[8];
#pragma unroll
    for (int kq = 0; kq < 8; kq++) {
      float a = 0.f;
#pragma unroll
      for (int d = 0; d < 32; d++)
        a += Bs[(b2 * 8 + q) * 128 + h * 32 + d] * Bs[2048 + (b2 * 8 + kq) * 128 + h * 32 + d];
      sc[kq] = a * 0.17677669529663688110f;
    }
    float mx = sc[0];
#pragma unroll
    for (int kq = 1; kq < 8; kq++) mx = fmaxf(mx, sc[kq]);
    float e[8], ssum = 0.f;
#pragma unroll
    for (int kq = 0; kq < 8; kq++) { e[kq] = expf(sc[kq] - mx); ssum += e[kq]; }
#pragma unroll
    for (int kq = 0; kq < 8; kq++)
      attbuf[((b2 * 4 + h) * 8 + q) * 8 + kq] = e[kq] / ssum;
  }
  __syncthreads();
  for (int idx = t; idx < 2048; idx += 256) {
    int r = idx >> 7, col = idx & 127, b2 = r >> 3, q = r & 7, h = col >> 5;
    float a = 0.f;
#pragma unroll
    for (int kq = 0; kq < 8; kq++)
      a += attbuf[((b2 * 4 + h) * 8 + q) * 8 + kq] * Bs[4096 + (b2 * 8 + kq) * 128 + col];
    inps_os[idx] = a;
  }
  __syncthreads();
  for (int idx = t; idx < 2048; idx += 256) {
    int r = idx >> 7, col = idx & 127;
    float af = IO<MODE>::ld(bf_c, col);
    float ag = IO<MODE>::ld(bg_c, col);
#pragma unroll 8
    for (int d = 0; d < 128; d++) {
      float o = inps_os[r * 128 + d];
      af += o * IO<MODE>::ld(Wf_c, d * 128 + col);
      ag += o * IO<MODE>::ld(Wg_c, d * 128 + col);
    }
    float comm = sigm(ag) * tanhf(af);
    float hv = (m8[r] != 0.f) ? (As[r * 128 + col] + comm)
                              : IO<MODE>::ld(hx, gbase + idx);
    IO<MODE>::st(out_hx, gbase + idx, hv);
  }
}

// ============================ launch ============================
extern "C" void kernel_launch(void* const* d_in, const int* in_sizes, int n_in,
                              void* d_out, int out_size, void* d_ws, size_t ws_size,
                              hipStream_t stream) {
  const void* inp     = d_in[0];
  const void* hx      = d_in[1];
  const void* cx      = d_in[2];
  const void* Wq_i    = d_in[3];
  const void* Wk_i    = d_in[4];
  const void* Wv_i    = d_in[5];
  const void* Wq_c    = d_in[6];
  const void* Wk_c    = d_in[7];
  const void* Wv_c    = d_in[8];
  const void* Wf_c    = d_in[9];
  const void* bf_c    = d_in[10];
  const void* Wg_c    = d_in[11];
  const void* bg_c    = d_in[12];
  const void* W_ih    = d_in[13];
  const void* W_hh    = d_in[14];
  const void* b_ih    = d_in[15];
  const void* b_hh    = d_in[16];
  const void* W_read  = d_in[17];
  const void* W_write = d_in[18];

  auto off_f32 = [&](int e) -> float* { return (float*)d_out + e; };
  auto off_b16 = [&](int e) -> void* { return (void*)((bf16*)d_out + e); };

  if (ws_size >= WS2_NEED) {
    half_t* wsp = (half_t*)d_ws;
    float* gws = (float*)((char*)d_ws + 2 * F_END);
    float* hread = gws + G_HREAD;
    float* mask8 = gws + G_MASK8;
    int* flag = (int*)(gws + G_FLAG);
    k_detect<<<1, 256, 0, stream>>>(inp, flag);
    k_wsplit2<<<328, 256, 0, stream>>>(flag, (const float*)W_ih, (const float*)W_hh,
                                       (const float*)W_write,
                                       (const float*)Wq_c, (const float*)Wk_c,
                                       (const float*)Wv_c, (const float*)Wf_c,
                                       (const float*)Wg_c, wsp);
    kA<<<1024, 256, 0, stream>>>(flag, (const float*)inp, (const float*)hx,
                                 (const float*)Wq_i, (const float*)Wk_i,
                                 (const float*)Wv_i, (const float*)W_read,
                                 wsp + F_XH, wsp + F_XL, hread, mask8,
                                 off_f32(4194304), off_f32(6291456));
    kB<<<512, 512, 0, stream>>>(flag, wsp, (const float*)cx,
                                (const float*)b_ih, (const float*)b_hh,
                                hread, mask8, wsp + F_HB,
                                off_f32(2097152), off_f32(6307840));
    kC<<<1024, 256, 0, stream>>>(flag, wsp, wsp + F_HB, mask8, (const float*)hx,
                                 (const float*)bf_c, (const float*)bg_c, off_f32(0));
    k_scoff<1><<<1024, 256, 0, stream>>>(flag, inp, hx, cx, Wq_i, Wk_i, Wv_i,
                                         Wq_c, Wk_c, Wv_c, Wf_c, bf_c, Wg_c, bg_c,
                                         W_ih, W_hh, b_ih, b_hh, W_read, W_write,
                                         off_b16(0), off_b16(2097152), off_b16(4194304),
                                         off_b16(6291456), off_b16(6307840));
  } else if (ws_size >= WS_NEED) {
    half_t* wsp = (half_t*)d_ws;
    int* flag = (int*)((char*)d_ws + WS_FLAG_OFF);
    k_detect<<<1, 256, 0, stream>>>(inp, flag);
    k_wsplit<<<2400, 256, 0, stream>>>((const float*)W_ih, (const float*)W_hh,
                                       (const float*)W_write,
                                       (const float*)Wq_c, (const float*)Wk_c,
                                       (const float*)Wv_c, (const float*)Wf_c,
                                       (const float*)Wg_c, wsp);
    k_scoff_mfma<<<1024, 256, 0, stream>>>(flag, wsp,
        (const float*)inp, (const float*)hx, (const float*)cx,
        (const float*)Wq_i, (const float*)Wk_i, (const float*)Wv_i,
        (const float*)bf_c, (const float*)bg_c,
        (const float*)b_ih, (const float*)b_hh, (const float*)W_read,
        off_f32(0), off_f32(2097152), off_f32(4194304),
        off_f32(6291456), off_f32(6307840));
    k_scoff<1><<<1024, 256, 0, stream>>>(flag, inp, hx, cx, Wq_i, Wk_i, Wv_i,
                                         Wq_c, Wk_c, Wv_c, Wf_c, bf_c, Wg_c, bg_c,
                                         W_ih, W_hh, b_ih, b_hh, W_read, W_write,
                                         off_b16(0), off_b16(2097152), off_b16(4194304),
                                         off_b16(6291456), off_b16(6307840));
  } else {
    int* flag = (int*)d_ws;
    k_detect<<<1, 256, 0, stream>>>(inp, flag);
    k_scoff<0><<<1024, 256, 0, stream>>>(flag, inp, hx, cx, Wq_i, Wk_i, Wv_i,
                                         Wq_c, Wk_c, Wv_c, Wf_c, bf_c, Wg_c, bg_c,
                                         W_ih, W_hh, b_ih, b_hh, W_read, W_write,
                                         (void*)off_f32(0), (void*)off_f32(2097152),
                                         (void*)off_f32(4194304), (void*)off_f32(6291456),
                                         (void*)off_f32(6307840));
    k_scoff<1><<<1024, 256, 0, stream>>>(flag, inp, hx, cx, Wq_i, Wk_i, Wv_i,
                                         Wq_c, Wk_c, Wv_c, Wf_c, bf_c, Wg_c, bg_c,
                                         W_ih, W_hh, b_ih, b_hh, W_read, W_write,
                                         off_b16(0), off_b16(2097152), off_b16(4194304),
                                         off_b16(6291456), off_b16(6307840));
  }
}